// Round 1
// baseline (1340.639 us; speedup 1.0000x reference)
//
#include <hip/hip_runtime.h>
#include <math.h>

#define B_ 4
#define T_ 1024
#define HD_ 1024
#define NH_ 16
#define DH_ 64
#define DS_ 64
#define NBH (B_*NH_)                 // 64
#define MSZ (4194304)                // B*T*HD = B*NH*T*64, per-tensor f32 count

typedef float f4 __attribute__((ext_vector_type(4)));

// ---------------------------------------------------------------- zero accum
__global__ void k_zero(float* acc) {
    if (threadIdx.x < 2) acc[threadIdx.x] = 0.f;
}

// ---------------------------------------------------------------- QKV GEMM
// C[n,m] = sum_k data[n,k]*qkv_w[m,k] + qkv_b[m]; scatter into Qc/Kc/Vc [b,h,t,d]
__global__ __launch_bounds__(256) void k_qkv(const float* __restrict__ A,
        const float* __restrict__ W, const float* __restrict__ bias,
        float* __restrict__ Qc, float* __restrict__ Kc, float* __restrict__ Vc)
{
    __shared__ float At[16*132];
    __shared__ float Bt[16*132];
    const int tid = threadIdx.x;
    const int tx = tid & 15, ty = tid >> 4;
    const int m0 = blockIdx.x * 128;   // 0..23 -> 3072 cols
    const int n0 = blockIdx.y * 128;   // 0..31 -> 4096 rows

    float acc[2][2][4][4] = {};

    for (int k0 = 0; k0 < 1024; k0 += 16) {
        __syncthreads();
        #pragma unroll
        for (int l = 0; l < 2; ++l) {
            int fid = l*256 + tid;
            int row = fid >> 2, c4 = fid & 3;
            f4 a = *(const f4*)&A[(size_t)(n0+row)*1024 + k0 + c4*4];
            f4 w = *(const f4*)&W[(size_t)(m0+row)*1024 + k0 + c4*4];
            #pragma unroll
            for (int j = 0; j < 4; ++j) {
                At[(c4*4+j)*132 + row] = a[j];
                Bt[(c4*4+j)*132 + row] = w[j];
            }
        }
        __syncthreads();
        #pragma unroll
        for (int k = 0; k < 16; ++k) {
            f4 a0 = *(const f4*)&At[k*132 + ty*4];
            f4 a1 = *(const f4*)&At[k*132 + 64 + ty*4];
            f4 b0 = *(const f4*)&Bt[k*132 + tx*4];
            f4 b1 = *(const f4*)&Bt[k*132 + 64 + tx*4];
            #pragma unroll
            for (int i = 0; i < 4; ++i)
                #pragma unroll
                for (int j = 0; j < 4; ++j) {
                    acc[0][0][i][j] += a0[i]*b0[j];
                    acc[0][1][i][j] += a0[i]*b1[j];
                    acc[1][0][i][j] += a1[i]*b0[j];
                    acc[1][1][i][j] += a1[i]*b1[j];
                }
        }
    }
    #pragma unroll
    for (int ih = 0; ih < 2; ++ih)
    #pragma unroll
    for (int jh = 0; jh < 2; ++jh)
    #pragma unroll
    for (int i = 0; i < 4; ++i) {
        int n  = n0 + ih*64 + ty*4 + i;
        int mc = m0 + jh*64 + tx*4;
        f4 bb = *(const f4*)&bias[mc];
        f4 v;
        #pragma unroll
        for (int j = 0; j < 4; ++j) v[j] = acc[ih][jh][i][j] + bb[j];
        int js  = mc >> 10;
        int col = mc & 1023;
        int hh = col >> 6, dd = col & 63;
        float* dst = (js == 0) ? Qc : ((js == 1) ? Kc : Vc);
        size_t off = ((size_t)(((n >> 10) * NH_ + hh) * T_ + (n & 1023))) * 64 + dd;
        *(f4*)&dst[off] = v;
    }
}

// ---------------------------------------------------------------- out projection
// out[n,m] = sum_k ctx[n,k]*out_w[m,k] + out_b[m]
__global__ __launch_bounds__(256) void k_oproj(const float* __restrict__ A,
        const float* __restrict__ W, const float* __restrict__ bias,
        float* __restrict__ out)
{
    __shared__ float At[16*132];
    __shared__ float Bt[16*132];
    const int tid = threadIdx.x;
    const int tx = tid & 15, ty = tid >> 4;
    const int m0 = blockIdx.x * 128;   // 0..7
    const int n0 = blockIdx.y * 128;   // 0..31

    float acc[2][2][4][4] = {};

    for (int k0 = 0; k0 < 1024; k0 += 16) {
        __syncthreads();
        #pragma unroll
        for (int l = 0; l < 2; ++l) {
            int fid = l*256 + tid;
            int row = fid >> 2, c4 = fid & 3;
            f4 a = *(const f4*)&A[(size_t)(n0+row)*1024 + k0 + c4*4];
            f4 w = *(const f4*)&W[(size_t)(m0+row)*1024 + k0 + c4*4];
            #pragma unroll
            for (int j = 0; j < 4; ++j) {
                At[(c4*4+j)*132 + row] = a[j];
                Bt[(c4*4+j)*132 + row] = w[j];
            }
        }
        __syncthreads();
        #pragma unroll
        for (int k = 0; k < 16; ++k) {
            f4 a0 = *(const f4*)&At[k*132 + ty*4];
            f4 a1 = *(const f4*)&At[k*132 + 64 + ty*4];
            f4 b0 = *(const f4*)&Bt[k*132 + tx*4];
            f4 b1 = *(const f4*)&Bt[k*132 + 64 + tx*4];
            #pragma unroll
            for (int i = 0; i < 4; ++i)
                #pragma unroll
                for (int j = 0; j < 4; ++j) {
                    acc[0][0][i][j] += a0[i]*b0[j];
                    acc[0][1][i][j] += a0[i]*b1[j];
                    acc[1][0][i][j] += a1[i]*b0[j];
                    acc[1][1][i][j] += a1[i]*b1[j];
                }
        }
    }
    #pragma unroll
    for (int ih = 0; ih < 2; ++ih)
    #pragma unroll
    for (int jh = 0; jh < 2; ++jh)
    #pragma unroll
    for (int i = 0; i < 4; ++i) {
        int n  = n0 + ih*64 + ty*4 + i;
        int mc = m0 + jh*64 + tx*4;
        f4 bb = *(const f4*)&bias[mc];
        f4 v;
        #pragma unroll
        for (int j = 0; j < 4; ++j) v[j] = acc[ih][jh][i][j] + bb[j];
        *(f4*)&out[(size_t)n*1024 + mc] = v;
    }
}

// ---------------------------------------------------------------- scratch projections
// out[b,h,t,d] = sum_s scratch_in[b,h,t,s] * W[h,s,d]  for W in {Wq_s,Wk_s,Wv_s}
__global__ __launch_bounds__(256) void k_sproj(const float* __restrict__ sin_,
        const float* __restrict__ Wq, const float* __restrict__ Wk, const float* __restrict__ Wv,
        float* __restrict__ Qs, float* __restrict__ Ks, float* __restrict__ Vs)
{
    __shared__ float inT[64*132];   // [s][t]
    __shared__ float Wt[64*68];     // [s][d]
    const int tid = threadIdx.x;
    const int tx = tid & 15, ty = tid >> 4;
    const int bh = blockIdx.y;
    const int h  = bh & (NH_-1);
    const int t0 = blockIdx.x * 128;
    const size_t base = ((size_t)bh * T_ + t0) * 64;

    #pragma unroll
    for (int l = 0; l < 8; ++l) {
        int fid = l*256 + tid;
        int row = fid >> 4, c4 = fid & 15;
        f4 a = *(const f4*)&sin_[base + (size_t)row*64 + c4*4];
        #pragma unroll
        for (int j = 0; j < 4; ++j) inT[(c4*4+j)*132 + row] = a[j];
    }

    for (int w = 0; w < 3; ++w) {
        const float* Wp = (w == 0) ? Wq : ((w == 1) ? Wk : Wv);
        float*       Op = (w == 0) ? Qs : ((w == 1) ? Ks : Vs);
        __syncthreads();
        #pragma unroll
        for (int l = 0; l < 4; ++l) {
            int fid = l*256 + tid;
            int s = fid >> 4, c4 = fid & 15;
            *(f4*)&Wt[s*68 + c4*4] = *(const f4*)&Wp[(size_t)h*4096 + s*64 + c4*4];
        }
        __syncthreads();
        float acc[8][4] = {};
        #pragma unroll 8
        for (int s = 0; s < 64; ++s) {
            f4 w4 = *(const f4*)&Wt[s*68 + tx*4];
            f4 a0 = *(const f4*)&inT[s*132 + ty*8];
            f4 a1 = *(const f4*)&inT[s*132 + ty*8 + 4];
            #pragma unroll
            for (int r = 0; r < 4; ++r)
                #pragma unroll
                for (int j = 0; j < 4; ++j) {
                    acc[r][j]   += a0[r]*w4[j];
                    acc[4+r][j] += a1[r]*w4[j];
                }
        }
        #pragma unroll
        for (int r = 0; r < 8; ++r) {
            f4 v;
            #pragma unroll
            for (int j = 0; j < 4; ++j) v[j] = acc[r][j];
            *(f4*)&Op[base + (size_t)(ty*8+r)*64 + tx*4] = v;
        }
    }
}

// ---------------------------------------------------------------- flash attention + stats
__global__ __launch_bounds__(256) void k_attn(
        const float* __restrict__ Qc, const float* __restrict__ Kc, const float* __restrict__ Vc,
        const float* __restrict__ Qs, const float* __restrict__ Ks, const float* __restrict__ Vs,
        const float* __restrict__ lam, const float* __restrict__ phv,
        float* __restrict__ ctx, float* __restrict__ out2, float* __restrict__ accum)
{
    __shared__ float smem[7*64*68 + 3*64 + 256];   // ~124 KB
    float* Qct = smem;            // [d][q]
    float* Qst = Qct + 64*68;
    float* Kct = Qst + 64*68;     // [d][k]
    float* Kst = Kct + 64*68;
    float* Vct = Kst + 64*68;     // [k][d]
    float* Vst = Vct + 64*68;
    float* St  = Vst + 64*68;     // [k][q] -> becomes P^T
    float* mrow = St + 64*68;
    float* lrow = mrow + 64;
    float* rfac = lrow + 64;
    float* red  = rfac + 64;      // [256]

    const int tid = threadIdx.x;
    const int tx = tid & 15, ty = tid >> 4;
    const int qt = blockIdx.x;        // 0..15
    const int bh = blockIdx.y;        // 0..63
    const int h  = bh & (NH_-1);
    const int q0 = qt * 64;
    const size_t bhbase = (size_t)bh * T_ * 64;

    const float lv = lam[0];
    const float coef = (lv > 1e-8f ? lv : 0.f) * expf(phv[h]);

    #pragma unroll
    for (int l = 0; l < 4; ++l) {
        int fid = l*256 + tid;
        int row = fid >> 4, c4 = fid & 15;
        f4 a = *(const f4*)&Qc[bhbase + (size_t)(q0+row)*64 + c4*4];
        f4 s = *(const f4*)&Qs[bhbase + (size_t)(q0+row)*64 + c4*4];
        #pragma unroll
        for (int j = 0; j < 4; ++j) {
            Qct[(c4*4+j)*68 + row] = a[j];
            Qst[(c4*4+j)*68 + row] = s[j];
        }
    }
    if (tid < 64) { mrow[tid] = -INFINITY; lrow[tid] = 0.f; }

    float acc_c[4][4] = {}, acc_s[4][4] = {};
    float s_c[4] = {}, qq_c[4] = {}, s_s[4] = {}, qq_s[4] = {};
    float d2 = 0.f;

    for (int kt = 0; kt < 16; ++kt) {
        __syncthreads();
        const size_t kb = bhbase + (size_t)kt*64*64;
        const bool pv = (kt <= qt);
        #pragma unroll
        for (int l = 0; l < 4; ++l) {
            int fid = l*256 + tid;
            int row = fid >> 4, c4 = fid & 15;
            f4 a = *(const f4*)&Kc[kb + (size_t)row*64 + c4*4];
            f4 s = *(const f4*)&Ks[kb + (size_t)row*64 + c4*4];
            #pragma unroll
            for (int j = 0; j < 4; ++j) {
                Kct[(c4*4+j)*68 + row] = a[j];
                Kst[(c4*4+j)*68 + row] = s[j];
            }
            if (pv) {
                *(f4*)&Vct[row*68 + c4*4] = *(const f4*)&Vc[kb + (size_t)row*64 + c4*4];
                *(f4*)&Vst[row*68 + c4*4] = *(const f4*)&Vs[kb + (size_t)row*64 + c4*4];
            }
        }
        __syncthreads();

        float Sc[4][4] = {}, Ss[4][4] = {};
        #pragma unroll 8
        for (int d = 0; d < 64; ++d) {
            f4 qc = *(const f4*)&Qct[d*68 + ty*4];
            f4 kc = *(const f4*)&Kct[d*68 + tx*4];
            f4 qs = *(const f4*)&Qst[d*68 + ty*4];
            f4 ks = *(const f4*)&Kst[d*68 + tx*4];
            #pragma unroll
            for (int i = 0; i < 4; ++i)
                #pragma unroll
                for (int j = 0; j < 4; ++j) {
                    Sc[i][j] += qc[i]*kc[j];
                    Ss[i][j] += qs[i]*ks[j];
                }
        }
        #pragma unroll
        for (int i = 0; i < 4; ++i)
            #pragma unroll
            for (int j = 0; j < 4; ++j) {
                float c = Sc[i][j] * 0.125f;
                float s = Ss[i][j] * 0.125f;
                Sc[i][j] = c; Ss[i][j] = s;
                float dl = coef * s;
                d2 += dl*dl;
                s_c[i] += c; qq_c[i] += c*c;
                s_s[i] += s; qq_s[i] += s*s;
            }
        if (!pv) continue;   // block-uniform

        const bool diag = (kt == qt);
        #pragma unroll
        for (int j = 0; j < 4; ++j) {
            int k_abs = kt*64 + tx*4 + j;
            f4 col;
            #pragma unroll
            for (int i = 0; i < 4; ++i) {
                float v = Sc[i][j] + coef * Ss[i][j];
                if (diag && k_abs > q0 + ty*4 + i) v = -INFINITY;
                col[i] = v;
            }
            *(f4*)&St[(tx*4+j)*68 + ty*4] = col;
        }
        __syncthreads();

        const int row = tid >> 2, sub = tid & 3;
        float pm = -INFINITY;
        #pragma unroll
        for (int kk = 0; kk < 16; ++kk)
            pm = fmaxf(pm, St[(sub*16+kk)*68 + row]);
        red[row*4+sub] = pm;
        __syncthreads();
        if (sub == 0) {
            float tm = fmaxf(fmaxf(red[row*4], red[row*4+1]), fmaxf(red[row*4+2], red[row*4+3]));
            float mo = mrow[row];
            float mn = fmaxf(mo, tm);
            float r  = __expf(mo - mn);
            mrow[row] = mn; rfac[row] = r; lrow[row] *= r;
        }
        __syncthreads();
        const float mN = mrow[row];
        float es = 0.f;
        #pragma unroll
        for (int kk = 0; kk < 16; ++kk) {
            int k = sub*16 + kk;
            float p = __expf(St[k*68 + row] - mN);
            St[k*68 + row] = p;
            es += p;
        }
        red[row*4+sub] = es;
        __syncthreads();
        if (sub == 0) lrow[row] += red[row*4] + red[row*4+1] + red[row*4+2] + red[row*4+3];

        float rf[4];
        #pragma unroll
        for (int i = 0; i < 4; ++i) rf[i] = rfac[ty*4+i];
        #pragma unroll
        for (int i = 0; i < 4; ++i)
            #pragma unroll
            for (int j = 0; j < 4; ++j) { acc_c[i][j] *= rf[i]; acc_s[i][j] *= rf[i]; }
        #pragma unroll 4
        for (int k = 0; k < 64; ++k) {
            f4 p  = *(const f4*)&St [k*68 + ty*4];
            f4 vc = *(const f4*)&Vct[k*68 + tx*4];
            f4 vs = *(const f4*)&Vst[k*68 + tx*4];
            #pragma unroll
            for (int i = 0; i < 4; ++i)
                #pragma unroll
                for (int j = 0; j < 4; ++j) {
                    acc_c[i][j] += p[i]*vc[j];
                    acc_s[i][j] += p[i]*vs[j];
                }
        }
    }

    __syncthreads();   // lrow final + LDS free for reuse

    float linv[4];
    #pragma unroll
    for (int i = 0; i < 4; ++i) linv[i] = 1.f / lrow[ty*4+i];
    const int b = bh >> 4;
    #pragma unroll
    for (int i = 0; i < 4; ++i) {
        int q = q0 + ty*4 + i;
        f4 oc, os;
        #pragma unroll
        for (int j = 0; j < 4; ++j) {
            oc[j] = acc_c[i][j] * linv[i];
            os[j] = acc_s[i][j] * linv[i];
        }
        *(f4*)&ctx [(((size_t)b*T_ + q)*NH_ + h)*64 + tx*4] = oc;
        *(f4*)&out2[((size_t)bh*T_ + q)*64 + tx*4] = os;
    }

    // row-std stats: reuse Kct region as 4 x [64][16]
    float* sb = Kct;
    #pragma unroll
    for (int i = 0; i < 4; ++i) {
        int r = ty*4 + i;
        sb[        r*16 + tx] = s_c[i];
        sb[1024 +  r*16 + tx] = qq_c[i];
        sb[2048 +  r*16 + tx] = s_s[i];
        sb[3072 +  r*16 + tx] = qq_s[i];
    }
    St[tid] = d2;
    __syncthreads();
    if (tid < 64) {
        float s1=0.f, s2=0.f, s3=0.f, s4=0.f;
        for (int x = 0; x < 16; ++x) {
            s1 += sb[        tid*16 + x];
            s2 += sb[1024 +  tid*16 + x];
            s3 += sb[2048 +  tid*16 + x];
            s4 += sb[3072 +  tid*16 + x];
        }
        float varc = (s2 - s1*s1*(1.f/1024.f)) * (1.f/1023.f);
        float vars = (s4 - s3*s3*(1.f/1024.f)) * (1.f/1023.f);
        float ratio = sqrtf(fmaxf(vars, 0.f)) / (sqrtf(fmaxf(varc, 0.f)) + 1e-6f);
        rfac[tid] = ratio;
    }
    __syncthreads();
    if (tid == 0) {
        float td2 = 0.f;
        for (int x = 0; x < 256; ++x) td2 += St[x];
        float tr = 0.f;
        for (int x = 0; x < 64; ++x) tr += rfac[x];
        atomicAdd(&accum[0], td2);
        atomicAdd(&accum[1], tr);
    }
}

// ---------------------------------------------------------------- finalize scalars
__global__ void k_fin(const float* __restrict__ acc, float* __restrict__ out) {
    if (threadIdx.x == 0) {
        out[0] = sqrtf(acc[0] * (1.f/67108864.f));   // / (B*NH*T*T)
        out[1] = acc[1] * (1.f/65536.f);             // / (B*NH*T)
    }
}

extern "C" void kernel_launch(void* const* d_in, const int* in_sizes, int n_in,
                              void* d_out, int out_size, void* d_ws, size_t ws_size,
                              hipStream_t stream)
{
    const float* data  = (const float*)d_in[0];
    const float* sin_  = (const float*)d_in[1];
    const float* qkv_w = (const float*)d_in[2];
    const float* qkv_b = (const float*)d_in[3];
    const float* out_w = (const float*)d_in[4];
    const float* out_b = (const float*)d_in[5];
    const float* Wq    = (const float*)d_in[6];
    const float* Wk    = (const float*)d_in[7];
    const float* Wv    = (const float*)d_in[8];
    const float* lam   = (const float*)d_in[9];
    const float* phv   = (const float*)d_in[10];
    float* out = (float*)d_out;
    float* ws  = (float*)d_ws;

    float* Qc = ws;
    float* Kc = ws + (size_t)MSZ;
    float* Vc = ws + 2*(size_t)MSZ;
    float* Qs = ws + 3*(size_t)MSZ;
    float* Ks = ws + 4*(size_t)MSZ;
    float* Vs = ws + 5*(size_t)MSZ;
    float* ctx = ws + 6*(size_t)MSZ;
    float* accum = ws + 7*(size_t)MSZ;

    k_zero <<<1, 64, 0, stream>>>(accum);
    k_qkv  <<<dim3(24, 32), 256, 0, stream>>>(data, qkv_w, qkv_b, Qc, Kc, Vc);
    k_sproj<<<dim3(8, 64), 256, 0, stream>>>(sin_, Wq, Wk, Wv, Qs, Ks, Vs);
    k_attn <<<dim3(16, 64), 256, 0, stream>>>(Qc, Kc, Vc, Qs, Ks, Vs, lam, phv,
                                              ctx, out + (size_t)MSZ, accum);
    k_oproj<<<dim3(8, 32), 256, 0, stream>>>(ctx, out_w, out_b, out);
    k_fin  <<<1, 64, 0, stream>>>(accum, out + 2*(size_t)MSZ);
}

// Round 2
// 1017.581 us; speedup vs baseline: 1.3175x; 1.3175x over previous
//
#include <hip/hip_runtime.h>
#include <math.h>

#define B_ 4
#define T_ 1024
#define HD_ 1024
#define NH_ 16
#define DH_ 64
#define DS_ 64
#define MSZ (4194304)                // B*T*HD = B*NH*T*64, per-tensor f32 count

typedef float f4 __attribute__((ext_vector_type(4)));
typedef float f32x4 __attribute__((ext_vector_type(4)));
typedef __bf16 bf16x8 __attribute__((ext_vector_type(8)));
typedef __bf16 bf16x4 __attribute__((ext_vector_type(4)));

static __device__ __forceinline__ f32x4 mfma16(bf16x8 a, bf16x8 b, f32x4 c) {
    return __builtin_amdgcn_mfma_f32_16x16x32_bf16(a, b, c, 0, 0, 0);
}

static __device__ __forceinline__ bf16x8 load8_bf16(const float* p) {
    f4 a = *(const f4*)p;
    f4 b = *(const f4*)(p + 4);
    bf16x8 r;
    r[0]=(__bf16)a[0]; r[1]=(__bf16)a[1]; r[2]=(__bf16)a[2]; r[3]=(__bf16)a[3];
    r[4]=(__bf16)b[0]; r[5]=(__bf16)b[1]; r[6]=(__bf16)b[2]; r[7]=(__bf16)b[3];
    return r;
}

// ---------------------------------------------------------------- zero accum
__global__ void k_zero(float* acc) {
    if (threadIdx.x < 2) acc[threadIdx.x] = 0.f;
}

// ---------------------------------------------------------------- QKV GEMM (fp32)
__global__ __launch_bounds__(256) void k_qkv(const float* __restrict__ A,
        const float* __restrict__ W, const float* __restrict__ bias,
        float* __restrict__ Qc, float* __restrict__ Kc, float* __restrict__ Vc)
{
    __shared__ float At[16*132];
    __shared__ float Bt[16*132];
    const int tid = threadIdx.x;
    const int tx = tid & 15, ty = tid >> 4;
    const int m0 = blockIdx.x * 128;
    const int n0 = blockIdx.y * 128;

    float acc[2][2][4][4] = {};

    for (int k0 = 0; k0 < 1024; k0 += 16) {
        __syncthreads();
        #pragma unroll
        for (int l = 0; l < 2; ++l) {
            int fid = l*256 + tid;
            int row = fid >> 2, c4 = fid & 3;
            f4 a = *(const f4*)&A[(size_t)(n0+row)*1024 + k0 + c4*4];
            f4 w = *(const f4*)&W[(size_t)(m0+row)*1024 + k0 + c4*4];
            #pragma unroll
            for (int j = 0; j < 4; ++j) {
                At[(c4*4+j)*132 + row] = a[j];
                Bt[(c4*4+j)*132 + row] = w[j];
            }
        }
        __syncthreads();
        #pragma unroll
        for (int k = 0; k < 16; ++k) {
            f4 a0 = *(const f4*)&At[k*132 + ty*4];
            f4 a1 = *(const f4*)&At[k*132 + 64 + ty*4];
            f4 b0 = *(const f4*)&Bt[k*132 + tx*4];
            f4 b1 = *(const f4*)&Bt[k*132 + 64 + tx*4];
            #pragma unroll
            for (int i = 0; i < 4; ++i)
                #pragma unroll
                for (int j = 0; j < 4; ++j) {
                    acc[0][0][i][j] += a0[i]*b0[j];
                    acc[0][1][i][j] += a0[i]*b1[j];
                    acc[1][0][i][j] += a1[i]*b0[j];
                    acc[1][1][i][j] += a1[i]*b1[j];
                }
        }
    }
    #pragma unroll
    for (int ih = 0; ih < 2; ++ih)
    #pragma unroll
    for (int jh = 0; jh < 2; ++jh)
    #pragma unroll
    for (int i = 0; i < 4; ++i) {
        int n  = n0 + ih*64 + ty*4 + i;
        int mc = m0 + jh*64 + tx*4;
        f4 bb = *(const f4*)&bias[mc];
        f4 v;
        #pragma unroll
        for (int j = 0; j < 4; ++j) v[j] = acc[ih][jh][i][j] + bb[j];
        int js  = mc >> 10;
        int col = mc & 1023;
        int hh = col >> 6, dd = col & 63;
        float* dst = (js == 0) ? Qc : ((js == 1) ? Kc : Vc);
        size_t off = ((size_t)(((n >> 10) * NH_ + hh) * T_ + (n & 1023))) * 64 + dd;
        *(f4*)&dst[off] = v;
    }
}

// ---------------------------------------------------------------- out projection (fp32)
__global__ __launch_bounds__(256) void k_oproj(const float* __restrict__ A,
        const float* __restrict__ W, const float* __restrict__ bias,
        float* __restrict__ out)
{
    __shared__ float At[16*132];
    __shared__ float Bt[16*132];
    const int tid = threadIdx.x;
    const int tx = tid & 15, ty = tid >> 4;
    const int m0 = blockIdx.x * 128;
    const int n0 = blockIdx.y * 128;

    float acc[2][2][4][4] = {};

    for (int k0 = 0; k0 < 1024; k0 += 16) {
        __syncthreads();
        #pragma unroll
        for (int l = 0; l < 2; ++l) {
            int fid = l*256 + tid;
            int row = fid >> 2, c4 = fid & 3;
            f4 a = *(const f4*)&A[(size_t)(n0+row)*1024 + k0 + c4*4];
            f4 w = *(const f4*)&W[(size_t)(m0+row)*1024 + k0 + c4*4];
            #pragma unroll
            for (int j = 0; j < 4; ++j) {
                At[(c4*4+j)*132 + row] = a[j];
                Bt[(c4*4+j)*132 + row] = w[j];
            }
        }
        __syncthreads();
        #pragma unroll
        for (int k = 0; k < 16; ++k) {
            f4 a0 = *(const f4*)&At[k*132 + ty*4];
            f4 a1 = *(const f4*)&At[k*132 + 64 + ty*4];
            f4 b0 = *(const f4*)&Bt[k*132 + tx*4];
            f4 b1 = *(const f4*)&Bt[k*132 + 64 + tx*4];
            #pragma unroll
            for (int i = 0; i < 4; ++i)
                #pragma unroll
                for (int j = 0; j < 4; ++j) {
                    acc[0][0][i][j] += a0[i]*b0[j];
                    acc[0][1][i][j] += a0[i]*b1[j];
                    acc[1][0][i][j] += a1[i]*b0[j];
                    acc[1][1][i][j] += a1[i]*b1[j];
                }
        }
    }
    #pragma unroll
    for (int ih = 0; ih < 2; ++ih)
    #pragma unroll
    for (int jh = 0; jh < 2; ++jh)
    #pragma unroll
    for (int i = 0; i < 4; ++i) {
        int n  = n0 + ih*64 + ty*4 + i;
        int mc = m0 + jh*64 + tx*4;
        f4 bb = *(const f4*)&bias[mc];
        f4 v;
        #pragma unroll
        for (int j = 0; j < 4; ++j) v[j] = acc[ih][jh][i][j] + bb[j];
        *(f4*)&out[(size_t)n*1024 + mc] = v;
    }
}

// ---------------------------------------------------------------- scratch projections (fp32)
__global__ __launch_bounds__(256) void k_sproj(const float* __restrict__ sin_,
        const float* __restrict__ Wq, const float* __restrict__ Wk, const float* __restrict__ Wv,
        float* __restrict__ Qs, float* __restrict__ Ks, float* __restrict__ Vs)
{
    __shared__ float inT[64*132];
    __shared__ float Wt[64*68];
    const int tid = threadIdx.x;
    const int tx = tid & 15, ty = tid >> 4;
    const int bh = blockIdx.y;
    const int h  = bh & (NH_-1);
    const int t0 = blockIdx.x * 128;
    const size_t base = ((size_t)bh * T_ + t0) * 64;

    #pragma unroll
    for (int l = 0; l < 8; ++l) {
        int fid = l*256 + tid;
        int row = fid >> 4, c4 = fid & 15;
        f4 a = *(const f4*)&sin_[base + (size_t)row*64 + c4*4];
        #pragma unroll
        for (int j = 0; j < 4; ++j) inT[(c4*4+j)*132 + row] = a[j];
    }

    for (int w = 0; w < 3; ++w) {
        const float* Wp = (w == 0) ? Wq : ((w == 1) ? Wk : Wv);
        float*       Op = (w == 0) ? Qs : ((w == 1) ? Ks : Vs);
        __syncthreads();
        #pragma unroll
        for (int l = 0; l < 4; ++l) {
            int fid = l*256 + tid;
            int s = fid >> 4, c4 = fid & 15;
            *(f4*)&Wt[s*68 + c4*4] = *(const f4*)&Wp[(size_t)h*4096 + s*64 + c4*4];
        }
        __syncthreads();
        float acc[8][4] = {};
        #pragma unroll 8
        for (int s = 0; s < 64; ++s) {
            f4 w4 = *(const f4*)&Wt[s*68 + tx*4];
            f4 a0 = *(const f4*)&inT[s*132 + ty*8];
            f4 a1 = *(const f4*)&inT[s*132 + ty*8 + 4];
            #pragma unroll
            for (int r = 0; r < 4; ++r)
                #pragma unroll
                for (int j = 0; j < 4; ++j) {
                    acc[r][j]   += a0[r]*w4[j];
                    acc[4+r][j] += a1[r]*w4[j];
                }
        }
        #pragma unroll
        for (int r = 0; r < 8; ++r) {
            f4 v;
            #pragma unroll
            for (int j = 0; j < 4; ++j) v[j] = acc[r][j];
            *(f4*)&Op[base + (size_t)(ty*8+r)*64 + tx*4] = v;
        }
    }
}

// ---------------------------------------------------------------- MFMA flash attention + stats
// QTILE=128 (4 waves x 32 rows), KTILE=64. bf16 inputs, fp32 accumulate.
// LDS (bf16, XOR-swizzled idx^=(row&7)<<3): K/Ks [key][d], V/Vs transposed [d][key], P [qrow][key].
__global__ __launch_bounds__(256, 2) void k_attn(
        const float* __restrict__ Qc, const float* __restrict__ Kc, const float* __restrict__ Vc,
        const float* __restrict__ Qs, const float* __restrict__ Ks, const float* __restrict__ Vs,
        const float* __restrict__ lam, const float* __restrict__ phv,
        float* __restrict__ ctx, float* __restrict__ out2, float* __restrict__ accum)
{
    __shared__ __bf16 sKC[4096];
    __shared__ __bf16 sKS[4096];
    __shared__ __bf16 sVC[4096];   // transposed [d][key]
    __shared__ __bf16 sVS[4096];
    __shared__ __bf16 sP[8192];    // [128 qrow][64 key]
    __shared__ float sred[8];

    const int tid  = threadIdx.x;
    const int lane = tid & 63;
    const int wid  = tid >> 6;
    const int lr   = lane & 15;    // frag row/col lane
    const int lg   = lane >> 4;    // frag k-group / C row-group
    const int bh   = blockIdx.x;   // 0..63
    const int qt   = blockIdx.y;   // 0..7
    const int h    = bh & (NH_-1);
    const int b    = bh >> 4;
    const int q0   = qt * 128;
    const size_t bhbase = (size_t)bh * T_ * 64;

    const float lv   = lam[0];
    const float coef = (lv > 1e-8f ? lv : 0.f) * __expf(phv[h]);

    // ---- hoist Q fragments (bf16) straight from global
    bf16x8 qcf[2][2], qsf[2][2];
    #pragma unroll
    for (int rf = 0; rf < 2; ++rf)
        #pragma unroll
        for (int hf = 0; hf < 2; ++hf) {
            int row = q0 + wid*32 + rf*16 + lr;
            int d0  = lg*8 + hf*32;
            qcf[rf][hf] = load8_bf16(&Qc[bhbase + (size_t)row*64 + d0]);
            qsf[rf][hf] = load8_bf16(&Qs[bhbase + (size_t)row*64 + d0]);
        }

    f32x4 Oc[2][4], Os[2][4];
    #pragma unroll
    for (int rf = 0; rf < 2; ++rf)
        #pragma unroll
        for (int n = 0; n < 4; ++n) { Oc[rf][n] = (f32x4){0,0,0,0}; Os[rf][n] = (f32x4){0,0,0,0}; }

    float m8[8], l8[8];
    float sc_s[8] = {}, qq_c[8] = {}, ss_s[8] = {}, qq_s[8] = {};
    #pragma unroll
    for (int i = 0; i < 8; ++i) { m8[i] = -INFINITY; l8[i] = 0.f; }

    for (int kt = 0; kt < 16; ++kt) {
        const bool pv = (kt <= 2*qt + 1);
        const size_t kb = bhbase + (size_t)kt*64*64;
        __syncthreads();
        // ---- stage K/Ks (row-major [key][d]) and V/Vs (transposed [d][key]) as bf16
        #pragma unroll
        for (int ph = 0; ph < 4; ++ph) {
            int fid = ph*256 + tid;
            int row = fid >> 4, q4 = fid & 15;
            {
                f4 v = *(const f4*)&Kc[kb + (size_t)row*64 + q4*4];
                bf16x4 hh; hh[0]=(__bf16)v[0]; hh[1]=(__bf16)v[1]; hh[2]=(__bf16)v[2]; hh[3]=(__bf16)v[3];
                *(bf16x4*)&sKC[((row<<6) + q4*4) ^ ((row&7)<<3)] = hh;
            }
            {
                f4 v = *(const f4*)&Ks[kb + (size_t)row*64 + q4*4];
                bf16x4 hh; hh[0]=(__bf16)v[0]; hh[1]=(__bf16)v[1]; hh[2]=(__bf16)v[2]; hh[3]=(__bf16)v[3];
                *(bf16x4*)&sKS[((row<<6) + q4*4) ^ ((row&7)<<3)] = hh;
            }
            if (pv) {
                f4 v = *(const f4*)&Vc[kb + (size_t)row*64 + q4*4];
                f4 w = *(const f4*)&Vs[kb + (size_t)row*64 + q4*4];
                #pragma unroll
                for (int j = 0; j < 4; ++j) {
                    int d = q4*4 + j;
                    sVC[((d<<6) + row) ^ ((d&7)<<3)] = (__bf16)v[j];
                    sVS[((d<<6) + row) ^ ((d&7)<<3)] = (__bf16)w[j];
                }
            }
        }
        __syncthreads();

        // ---- S = Q K^T (both streams), stats, combined logits
        float L[2][4][4];
        #pragma unroll
        for (int n = 0; n < 4; ++n) {
            int krow = n*16 + lr;
            int swz  = (krow&7) << 3;
            bf16x8 bkc0 = *(const bf16x8*)&sKC[((krow<<6) + lg*8     ) ^ swz];
            bf16x8 bkc1 = *(const bf16x8*)&sKC[((krow<<6) + lg*8 + 32) ^ swz];
            bf16x8 bks0 = *(const bf16x8*)&sKS[((krow<<6) + lg*8     ) ^ swz];
            bf16x8 bks1 = *(const bf16x8*)&sKS[((krow<<6) + lg*8 + 32) ^ swz];
            #pragma unroll
            for (int rf = 0; rf < 2; ++rf) {
                f32x4 z = {0.f,0.f,0.f,0.f};
                f32x4 sc = mfma16(qcf[rf][1], bkc1, mfma16(qcf[rf][0], bkc0, z));
                f32x4 ss = mfma16(qsf[rf][1], bks1, mfma16(qsf[rf][0], bks0, z));
                #pragma unroll
                for (int r = 0; r < 4; ++r) {
                    int i = rf*4 + r;
                    sc_s[i] += sc[r];
                    qq_c[i] = fmaf(sc[r], sc[r], qq_c[i]);
                    ss_s[i] += ss[r];
                    qq_s[i] = fmaf(ss[r], ss[r], qq_s[i]);
                    L[rf][n][r] = 0.125f * fmaf(coef, ss[r], sc[r]);
                }
            }
        }
        if (!pv) continue;

        // ---- causal mask (only diag-region tiles)
        if (kt >= 2*qt) {
            #pragma unroll
            for (int rf = 0; rf < 2; ++rf)
                #pragma unroll
                for (int n = 0; n < 4; ++n) {
                    int col = kt*64 + n*16 + lr;
                    #pragma unroll
                    for (int r = 0; r < 4; ++r) {
                        int row = q0 + wid*32 + rf*16 + lg*4 + r;
                        if (col > row) L[rf][n][r] = -INFINITY;
                    }
                }
        }

        // ---- online softmax
        float fr8[8];
        #pragma unroll
        for (int i = 0; i < 8; ++i) {
            int rf = i >> 2, r = i & 3;
            float v = fmaxf(fmaxf(L[rf][0][r], L[rf][1][r]), fmaxf(L[rf][2][r], L[rf][3][r]));
            v = fmaxf(v, __shfl_xor(v, 1));
            v = fmaxf(v, __shfl_xor(v, 2));
            v = fmaxf(v, __shfl_xor(v, 4));
            v = fmaxf(v, __shfl_xor(v, 8));
            float mn = fmaxf(m8[i], v);
            float fr = __expf(m8[i] - mn);
            m8[i] = mn; fr8[i] = fr;
            float ps = 0.f;
            #pragma unroll
            for (int n = 0; n < 4; ++n) {
                float p = __expf(L[rf][n][r] - mn);
                L[rf][n][r] = p;
                ps += p;
            }
            l8[i] = l8[i]*fr + ps;
        }
        #pragma unroll
        for (int rf = 0; rf < 2; ++rf)
            #pragma unroll
            for (int n = 0; n < 4; ++n)
                #pragma unroll
                for (int r = 0; r < 4; ++r) {
                    Oc[rf][n][r] *= fr8[rf*4+r];
                    Os[rf][n][r] *= fr8[rf*4+r];
                }

        // ---- write P (bf16) to wave-local LDS strip
        #pragma unroll
        for (int rf = 0; rf < 2; ++rf)
            #pragma unroll
            for (int n = 0; n < 4; ++n)
                #pragma unroll
                for (int r = 0; r < 4; ++r) {
                    int prow = wid*32 + rf*16 + lg*4 + r;
                    sP[((prow<<6) + n*16 + lr) ^ ((prow&7)<<3)] = (__bf16)L[rf][n][r];
                }

        // ---- O += P V (both streams)
        bf16x8 pa[2][2];
        #pragma unroll
        for (int rf = 0; rf < 2; ++rf)
            #pragma unroll
            for (int hf = 0; hf < 2; ++hf) {
                int prow = wid*32 + rf*16 + lr;
                pa[rf][hf] = *(const bf16x8*)&sP[((prow<<6) + lg*8 + hf*32) ^ ((prow&7)<<3)];
            }
        #pragma unroll
        for (int n = 0; n < 4; ++n) {
            int vrow = n*16 + lr;
            int swz  = (vrow&7) << 3;
            bf16x8 bvc0 = *(const bf16x8*)&sVC[((vrow<<6) + lg*8     ) ^ swz];
            bf16x8 bvc1 = *(const bf16x8*)&sVC[((vrow<<6) + lg*8 + 32) ^ swz];
            bf16x8 bvs0 = *(const bf16x8*)&sVS[((vrow<<6) + lg*8     ) ^ swz];
            bf16x8 bvs1 = *(const bf16x8*)&sVS[((vrow<<6) + lg*8 + 32) ^ swz];
            #pragma unroll
            for (int rf = 0; rf < 2; ++rf) {
                Oc[rf][n] = mfma16(pa[rf][1], bvc1, mfma16(pa[rf][0], bvc0, Oc[rf][n]));
                Os[rf][n] = mfma16(pa[rf][1], bvs1, mfma16(pa[rf][0], bvs0, Os[rf][n]));
            }
        }
    }

    // ---- d2 partial BEFORE cross-lane stat reduction (per-lane partials are disjoint)
    float d2p = 0.f;
    #pragma unroll
    for (int i = 0; i < 8; ++i) d2p += qq_s[i];

    // ---- reduce row sums across the 16 col-lanes
    #pragma unroll
    for (int i = 0; i < 8; ++i) {
        #pragma unroll
        for (int msk = 1; msk <= 8; msk <<= 1) {
            l8[i]   += __shfl_xor(l8[i],   msk);
            sc_s[i] += __shfl_xor(sc_s[i], msk);
            qq_c[i] += __shfl_xor(qq_c[i], msk);
            ss_s[i] += __shfl_xor(ss_s[i], msk);
            qq_s[i] += __shfl_xor(qq_s[i], msk);
        }
    }

    // ---- outputs
    #pragma unroll
    for (int rf = 0; rf < 2; ++rf)
        #pragma unroll
        for (int r = 0; r < 4; ++r) {
            int i = rf*4 + r;
            float linv = 1.0f / l8[i];
            int row = q0 + wid*32 + rf*16 + lg*4 + r;
            #pragma unroll
            for (int n = 0; n < 4; ++n) {
                int d = n*16 + lr;
                ctx [(((size_t)b*T_ + row)*NH_ + h)*64 + d] = Oc[rf][n][r] * linv;
                out2[((size_t)bh*T_ + row)*64 + d]          = Os[rf][n][r] * linv;
            }
        }

    // ---- row-std ratios (each row replicated on 16 lanes -> 1/16 weight)
    float rp = 0.f;
    #pragma unroll
    for (int i = 0; i < 8; ++i) {
        float S1c = 0.125f    * sc_s[i];
        float S2c = 0.015625f * qq_c[i];
        float S1s = 0.125f    * ss_s[i];
        float S2s = 0.015625f * qq_s[i];
        float varc = (S2c - S1c*S1c*(1.f/1024.f)) * (1.f/1023.f);
        float vars = (S2s - S1s*S1s*(1.f/1024.f)) * (1.f/1023.f);
        rp += sqrtf(fmaxf(vars, 0.f)) / (sqrtf(fmaxf(varc, 0.f)) + 1e-6f);
    }
    rp *= (1.f/16.f);

    // ---- block reduce + atomics
    #pragma unroll
    for (int msk = 1; msk <= 32; msk <<= 1) {
        d2p += __shfl_xor(d2p, msk);
        rp  += __shfl_xor(rp,  msk);
    }
    if (lane == 0) { sred[wid] = d2p; sred[4+wid] = rp; }
    __syncthreads();
    if (tid == 0) {
        float td2 = (sred[0]+sred[1]+sred[2]+sred[3]) * coef * coef * 0.015625f;
        float tr  =  sred[4]+sred[5]+sred[6]+sred[7];
        atomicAdd(&accum[0], td2);
        atomicAdd(&accum[1], tr);
    }
}

// ---------------------------------------------------------------- finalize scalars
__global__ void k_fin(const float* __restrict__ acc, float* __restrict__ out) {
    if (threadIdx.x == 0) {
        out[0] = sqrtf(acc[0] * (1.f/67108864.f));   // / (B*NH*T*T)
        out[1] = acc[1] * (1.f/65536.f);             // / (B*NH*T)
    }
}

extern "C" void kernel_launch(void* const* d_in, const int* in_sizes, int n_in,
                              void* d_out, int out_size, void* d_ws, size_t ws_size,
                              hipStream_t stream)
{
    const float* data  = (const float*)d_in[0];
    const float* sin_  = (const float*)d_in[1];
    const float* qkv_w = (const float*)d_in[2];
    const float* qkv_b = (const float*)d_in[3];
    const float* out_w = (const float*)d_in[4];
    const float* out_b = (const float*)d_in[5];
    const float* Wq    = (const float*)d_in[6];
    const float* Wk    = (const float*)d_in[7];
    const float* Wv    = (const float*)d_in[8];
    const float* lam   = (const float*)d_in[9];
    const float* phv   = (const float*)d_in[10];
    float* out = (float*)d_out;
    float* ws  = (float*)d_ws;

    float* Qc = ws;
    float* Kc = ws + (size_t)MSZ;
    float* Vc = ws + 2*(size_t)MSZ;
    float* Qs = ws + 3*(size_t)MSZ;
    float* Ks = ws + 4*(size_t)MSZ;
    float* Vs = ws + 5*(size_t)MSZ;
    float* ctx = ws + 6*(size_t)MSZ;
    float* accum = ws + 7*(size_t)MSZ;

    k_zero <<<1, 64, 0, stream>>>(accum);
    k_qkv  <<<dim3(24, 32), 256, 0, stream>>>(data, qkv_w, qkv_b, Qc, Kc, Vc);
    k_sproj<<<dim3(8, 64), 256, 0, stream>>>(sin_, Wq, Wk, Wv, Qs, Ks, Vs);
    k_attn <<<dim3(64, 8), 256, 0, stream>>>(Qc, Kc, Vc, Qs, Ks, Vs, lam, phv,
                                             ctx, out + (size_t)MSZ, accum);
    k_oproj<<<dim3(8, 32), 256, 0, stream>>>(ctx, out_w, out_b, out);
    k_fin  <<<1, 64, 0, stream>>>(accum, out + 2*(size_t)MSZ);
}

// Round 3
// 498.573 us; speedup vs baseline: 2.6890x; 2.0410x over previous
//
#include <hip/hip_runtime.h>
#include <math.h>
#include <stdint.h>

#define B_ 4
#define T_ 1024
#define NH_ 16
#define MSZ (4194304)   // B*T*1024 elems

typedef float f4 __attribute__((ext_vector_type(4)));
typedef float f32x4 __attribute__((ext_vector_type(4)));
typedef __bf16 bf16x8 __attribute__((ext_vector_type(8)));
typedef __bf16 bf16x4 __attribute__((ext_vector_type(4)));

static __device__ __forceinline__ f32x4 mfma16(bf16x8 a, bf16x8 b, f32x4 c) {
    return __builtin_amdgcn_mfma_f32_16x16x32_bf16(a, b, c, 0, 0, 0);
}

// global -> LDS direct 16B copy (lane l writes dst + l*16)
static __device__ __forceinline__ void gld16(const void* g, void* l) {
    auto gp = reinterpret_cast<const uint32_t __attribute__((address_space(1)))*>(
        reinterpret_cast<uintptr_t>(g));
    auto lp = reinterpret_cast<uint32_t __attribute__((address_space(3)))*>(
        reinterpret_cast<uintptr_t>(l));
    __builtin_amdgcn_global_load_lds(gp, lp, 16, 0, 0);
}

// ---------------------------------------------------------------- zero accum
__global__ void k_zero(float* acc) {
    if (threadIdx.x < 2) acc[threadIdx.x] = 0.f;
}

// ---------------------------------------------------------------- split-bf16 MFMA GEMM
// C[n,m] = sum_k A[n,k]*W[m,k] + bias[m]; A,W f32; hi/lo bf16 split, 3 MFMA passes.
// MODE 0 (qkv): M=3072, outputs bf16 Qb/Kb ([bh][t][64]) and Vtb ([bh][d][t]).
// MODE 1 (oproj): M=1024, output f32 [n][m].
template<int MODE>
__global__ __launch_bounds__(256, 2) void k_gemm(
        const float* __restrict__ A, const float* __restrict__ W,
        const float* __restrict__ bias,
        __bf16* __restrict__ Qb, __bf16* __restrict__ Kb, __bf16* __restrict__ Vtb,
        float* __restrict__ outf)
{
    __shared__ __bf16 Ah[8192];   // [128][64] bf16, 128B rows, chunk-XOR swizzled
    __shared__ __bf16 Al[8192];
    __shared__ __bf16 Bh[8192];
    __shared__ __bf16 Bl[8192];

    const int tid  = threadIdx.x;
    const int lane = tid & 63;
    const int wid  = tid >> 6;
    const int lr   = lane & 15;
    const int lg   = lane >> 4;
    const int wr   = wid >> 1, wc = wid & 1;
    const int m0 = blockIdx.x * 128;
    const int n0 = blockIdx.y * 128;

    f32x4 acc[4][4];
    #pragma unroll
    for (int i = 0; i < 4; ++i)
        #pragma unroll
        for (int j = 0; j < 4; ++j) acc[i][j] = (f32x4){0.f,0.f,0.f,0.f};

    const int srow = tid >> 4, scol = tid & 15;   // staging: 16 rows/phase, 16 f4-cols

    for (int k0 = 0; k0 < 1024; k0 += 64) {
        __syncthreads();
        #pragma unroll
        for (int ph = 0; ph < 8; ++ph) {
            int row = ph*16 + srow;
            f4 a = *(const f4*)&A[(size_t)(n0+row)*1024 + k0 + scol*4];
            f4 w = *(const f4*)&W[(size_t)(m0+row)*1024 + k0 + scol*4];
            bf16x4 ahh, all_, whh, wll;
            #pragma unroll
            for (int j = 0; j < 4; ++j) {
                __bf16 h1 = (__bf16)a[j];
                ahh[j] = h1; all_[j] = (__bf16)(a[j] - (float)h1);
                __bf16 h2 = (__bf16)w[j];
                whh[j] = h2; wll[j] = (__bf16)(w[j] - (float)h2);
            }
            int byte = row*128 + (((scol>>1) ^ (row&7))<<4) + ((scol&1)<<3);
            *(bf16x4*)((char*)Ah + byte) = ahh;
            *(bf16x4*)((char*)Al + byte) = all_;
            *(bf16x4*)((char*)Bh + byte) = whh;
            *(bf16x4*)((char*)Bl + byte) = wll;
        }
        __syncthreads();

        #pragma unroll
        for (int kk = 0; kk < 2; ++kk) {
            bf16x8 ah[4], al[4], bh_[4], bl[4];
            #pragma unroll
            for (int rf = 0; rf < 4; ++rf) {
                int row = wr*64 + rf*16 + lr;
                int byte = row*128 + (((lg + 4*kk) ^ (row&7))<<4);
                ah[rf] = *(const bf16x8*)((const char*)Ah + byte);
                al[rf] = *(const bf16x8*)((const char*)Al + byte);
            }
            #pragma unroll
            for (int n = 0; n < 4; ++n) {
                int row = wc*64 + n*16 + lr;
                int byte = row*128 + (((lg + 4*kk) ^ (row&7))<<4);
                bh_[n] = *(const bf16x8*)((const char*)Bh + byte);
                bl[n] = *(const bf16x8*)((const char*)Bl + byte);
            }
            #pragma unroll
            for (int rf = 0; rf < 4; ++rf)
                #pragma unroll
                for (int n = 0; n < 4; ++n) {
                    acc[rf][n] = mfma16(al[rf], bh_[n], acc[rf][n]);
                    acc[rf][n] = mfma16(ah[rf], bl[n],  acc[rf][n]);
                    acc[rf][n] = mfma16(ah[rf], bh_[n], acc[rf][n]);
                }
        }
    }

    // epilogue
    #pragma unroll
    for (int n = 0; n < 4; ++n) {
        int col = m0 + wc*64 + n*16 + lr;
        float bb = bias[col];
        #pragma unroll
        for (int rf = 0; rf < 4; ++rf)
            #pragma unroll
            for (int r = 0; r < 4; ++r) {
                float v = acc[rf][n][r] + bb;
                int trow = n0 + wr*64 + rf*16 + lg*4 + r;
                if (MODE == 1) {
                    outf[(size_t)trow*1024 + col] = v;
                } else {
                    int js = col >> 10;
                    int hh = (col >> 6) & 15;
                    int dd = col & 63;
                    int b  = trow >> 10, t = trow & 1023;
                    int bh = b*16 + hh;
                    __bf16 bv = (__bf16)v;
                    if (js == 0)      Qb [((size_t)bh*1024 + t)*64 + dd] = bv;
                    else if (js == 1) Kb [((size_t)bh*1024 + t)*64 + dd] = bv;
                    else              Vtb[((size_t)bh*64 + dd)*1024 + t] = bv;
                }
            }
    }
}

// ---------------------------------------------------------------- scratch projections (f32 math, bf16 out)
__global__ __launch_bounds__(256) void k_sproj(const float* __restrict__ sin_,
        const float* __restrict__ Wq, const float* __restrict__ Wk, const float* __restrict__ Wv,
        __bf16* __restrict__ Qsb, __bf16* __restrict__ Ksb, __bf16* __restrict__ Vstb)
{
    __shared__ float inT[64*132];
    __shared__ float Wt[64*68];
    const int tid = threadIdx.x;
    const int tx = tid & 15, ty = tid >> 4;
    const int bh = blockIdx.y;
    const int h  = bh & (NH_-1);
    const int t0 = blockIdx.x * 128;
    const size_t base = ((size_t)bh * T_ + t0) * 64;

    #pragma unroll
    for (int l = 0; l < 8; ++l) {
        int fid = l*256 + tid;
        int row = fid >> 4, c4 = fid & 15;
        f4 a = *(const f4*)&sin_[base + (size_t)row*64 + c4*4];
        #pragma unroll
        for (int j = 0; j < 4; ++j) inT[(c4*4+j)*132 + row] = a[j];
    }

    for (int w = 0; w < 3; ++w) {
        const float* Wp = (w == 0) ? Wq : ((w == 1) ? Wk : Wv);
        __syncthreads();
        #pragma unroll
        for (int l = 0; l < 4; ++l) {
            int fid = l*256 + tid;
            int s = fid >> 4, c4 = fid & 15;
            *(f4*)&Wt[s*68 + c4*4] = *(const f4*)&Wp[(size_t)h*4096 + s*64 + c4*4];
        }
        __syncthreads();
        float acc[8][4] = {};
        #pragma unroll 8
        for (int s = 0; s < 64; ++s) {
            f4 w4 = *(const f4*)&Wt[s*68 + tx*4];
            f4 a0 = *(const f4*)&inT[s*132 + ty*8];
            f4 a1 = *(const f4*)&inT[s*132 + ty*8 + 4];
            #pragma unroll
            for (int r = 0; r < 4; ++r)
                #pragma unroll
                for (int j = 0; j < 4; ++j) {
                    acc[r][j]   += a0[r]*w4[j];
                    acc[4+r][j] += a1[r]*w4[j];
                }
        }
        if (w < 2) {
            __bf16* Op = (w == 0) ? Qsb : Ksb;
            #pragma unroll
            for (int r = 0; r < 8; ++r) {
                bf16x4 v;
                #pragma unroll
                for (int j = 0; j < 4; ++j) v[j] = (__bf16)acc[r][j];
                *(bf16x4*)&Op[base + (size_t)(ty*8+r)*64 + tx*4] = v;
            }
        } else {
            #pragma unroll
            for (int r = 0; r < 8; ++r)
                #pragma unroll
                for (int j = 0; j < 4; ++j)
                    Vstb[((size_t)bh*64 + tx*4+j)*1024 + t0 + ty*8 + r] = (__bf16)acc[r][j];
        }
    }
}

// ---------------------------------------------------------------- MFMA flash attention + stats
// QTILE=64 (4 waves x 16 rows), KTILE=64. All operands bf16 in global.
// K/Ks row-major [key][64]; V/Vs pre-transposed [d][t]. LDS staged via global_load_lds
// with inverse-swizzled source; reads use chunk-XOR swizzle (chunk ^= row&7).
__global__ __launch_bounds__(256, 3) void k_attn(
        const __bf16* __restrict__ Qcb, const __bf16* __restrict__ Kcb, const __bf16* __restrict__ Vtb,
        const __bf16* __restrict__ Qsb, const __bf16* __restrict__ Ksb, const __bf16* __restrict__ Vstb,
        const float* __restrict__ lam, const float* __restrict__ phv,
        float* __restrict__ ctx, float* __restrict__ out2, float* __restrict__ accum)
{
    __shared__ __bf16 sKC[4096];   // [64 key][64 d]
    __shared__ __bf16 sKS[4096];
    __shared__ __bf16 sVC[4096];   // [64 d][64 key]  (from Vtb)
    __shared__ __bf16 sVS[4096];
    __shared__ __bf16 sP [4096];   // [64 qrow][64 key], wave-local strips

    const int tid  = threadIdx.x;
    const int lane = tid & 63;
    const int wid  = tid >> 6;
    const int lr   = lane & 15;
    const int lg   = lane >> 4;
    const int bh   = blockIdx.x;          // 0..63
    const int qt   = 15 - blockIdx.y;     // reversed: heavy blocks first
    const int h    = bh & (NH_-1);
    const int b    = bh >> 4;
    const int q0   = qt * 64;

    const float lv   = lam[0];
    const float coef = (lv > 1e-8f ? lv : 0.f) * __expf(phv[h]);

    // Q fragments direct from global bf16
    bf16x8 qcf[2], qsf[2];
    {
        int row = q0 + wid*16 + lr;
        size_t qb = ((size_t)bh*1024 + row)*64;
        #pragma unroll
        for (int hf = 0; hf < 2; ++hf) {
            qcf[hf] = *(const bf16x8*)&Qcb[qb + hf*32 + lg*8];
            qsf[hf] = *(const bf16x8*)&Qsb[qb + hf*32 + lg*8];
        }
    }

    f32x4 Oc[4], Os[4];
    #pragma unroll
    for (int n = 0; n < 4; ++n) { Oc[n] = (f32x4){0,0,0,0}; Os[n] = (f32x4){0,0,0,0}; }

    float m4[4], l4[4];
    float sc_s[4] = {}, qq_c[4] = {}, ss_s[4] = {}, qq_s[4] = {};
    #pragma unroll
    for (int i = 0; i < 4; ++i) { m4[i] = -INFINITY; l4[i] = 0.f; }

    const char* kcB = (const char*)Kcb  + (size_t)bh*1024*128;
    const char* ksB = (const char*)Ksb  + (size_t)bh*1024*128;
    const char* vtB = (const char*)Vtb  + (size_t)bh*64*2048;
    const char* vsB = (const char*)Vstb + (size_t)bh*64*2048;

    for (int kt = 0; kt < 16; ++kt) {
        const bool pv = (kt <= qt);
        __syncthreads();
        // ---- stage via global_load_lds (each wave: 2 x 1KB per tile)
        #pragma unroll
        for (int c = 0; c < 2; ++c) {
            int trow = wid*16 + c*8 + (lane>>3);
            int sc_  = (lane&7) ^ (trow&7);
            size_t dsto = (size_t)wid*2048 + c*1024;
            gld16(kcB + ((size_t)(kt*64 + trow))*128 + sc_*16, (char*)sKC + dsto);
            gld16(ksB + ((size_t)(kt*64 + trow))*128 + sc_*16, (char*)sKS + dsto);
            if (pv) {
                gld16(vtB + (size_t)trow*2048 + kt*128 + sc_*16, (char*)sVC + dsto);
                gld16(vsB + (size_t)trow*2048 + kt*128 + sc_*16, (char*)sVS + dsto);
            }
        }
        __syncthreads();

        // ---- S = Q K^T both streams + stats
        float L[4][4];   // [n][r]
        #pragma unroll
        for (int n = 0; n < 4; ++n) {
            int krow = n*16 + lr;
            int rswz = krow & 7;
            const char* pc = (const char*)sKC + krow*128;
            const char* ps = (const char*)sKS + krow*128;
            bf16x8 kc0 = *(const bf16x8*)(pc + (((lg  ) ^ rswz)<<4));
            bf16x8 kc1 = *(const bf16x8*)(pc + (((lg+4) ^ rswz)<<4));
            bf16x8 ks0 = *(const bf16x8*)(ps + (((lg  ) ^ rswz)<<4));
            bf16x8 ks1 = *(const bf16x8*)(ps + (((lg+4) ^ rswz)<<4));
            f32x4 z = {0.f,0.f,0.f,0.f};
            f32x4 sc = mfma16(qcf[1], kc1, mfma16(qcf[0], kc0, z));
            f32x4 ss = mfma16(qsf[1], ks1, mfma16(qsf[0], ks0, z));
            #pragma unroll
            for (int r = 0; r < 4; ++r) {
                sc_s[r] += sc[r];
                qq_c[r] = fmaf(sc[r], sc[r], qq_c[r]);
                ss_s[r] += ss[r];
                qq_s[r] = fmaf(ss[r], ss[r], qq_s[r]);
                L[n][r] = 0.125f * fmaf(coef, ss[r], sc[r]);
            }
        }
        if (!pv) continue;

        // ---- causal mask on diagonal tile
        if (kt == qt) {
            #pragma unroll
            for (int n = 0; n < 4; ++n) {
                int kc = n*16 + lr;
                #pragma unroll
                for (int r = 0; r < 4; ++r)
                    if (kc > wid*16 + lg*4 + r) L[n][r] = -INFINITY;
            }
        }

        // ---- online softmax (rows = lg*4+r, cols split across 16 lr-lanes)
        float fr4[4];
        #pragma unroll
        for (int r = 0; r < 4; ++r) {
            float v = fmaxf(fmaxf(L[0][r], L[1][r]), fmaxf(L[2][r], L[3][r]));
            v = fmaxf(v, __shfl_xor(v, 1));
            v = fmaxf(v, __shfl_xor(v, 2));
            v = fmaxf(v, __shfl_xor(v, 4));
            v = fmaxf(v, __shfl_xor(v, 8));
            float mn = fmaxf(m4[r], v);
            float fr = __expf(m4[r] - mn);
            m4[r] = mn; fr4[r] = fr;
            float ps = 0.f;
            #pragma unroll
            for (int n = 0; n < 4; ++n) {
                float p = __expf(L[n][r] - mn);
                L[n][r] = p;
                ps += p;
            }
            l4[r] = l4[r]*fr + ps;
        }
        #pragma unroll
        for (int n = 0; n < 4; ++n)
            #pragma unroll
            for (int r = 0; r < 4; ++r) {
                Oc[n][r] *= fr4[r];
                Os[n][r] *= fr4[r];
            }

        // ---- P -> wave-local LDS strip (bf16, swizzled)
        #pragma unroll
        for (int n = 0; n < 4; ++n)
            #pragma unroll
            for (int r = 0; r < 4; ++r) {
                int prow = wid*16 + lg*4 + r;
                *((__bf16*)((char*)sP + prow*128 + ((((n*16+lr)>>3) ^ (prow&7))<<4) + (((n*16+lr)&7)<<1))) = (__bf16)L[n][r];
            }

        // ---- O += P V (both streams)
        bf16x8 pa[2];
        {
            int prow = wid*16 + lr;
            const char* pp = (const char*)sP + prow*128;
            pa[0] = *(const bf16x8*)(pp + (((lg  ) ^ (prow&7))<<4));
            pa[1] = *(const bf16x8*)(pp + (((lg+4) ^ (prow&7))<<4));
        }
        #pragma unroll
        for (int n = 0; n < 4; ++n) {
            int vrow = n*16 + lr;
            int rswz = vrow & 7;
            const char* pc = (const char*)sVC + vrow*128;
            const char* ps = (const char*)sVS + vrow*128;
            bf16x8 vc0 = *(const bf16x8*)(pc + (((lg  ) ^ rswz)<<4));
            bf16x8 vc1 = *(const bf16x8*)(pc + (((lg+4) ^ rswz)<<4));
            bf16x8 vs0 = *(const bf16x8*)(ps + (((lg  ) ^ rswz)<<4));
            bf16x8 vs1 = *(const bf16x8*)(ps + (((lg+4) ^ rswz)<<4));
            Oc[n] = mfma16(pa[1], vc1, mfma16(pa[0], vc0, Oc[n]));
            Os[n] = mfma16(pa[1], vs1, mfma16(pa[0], vs0, Os[n]));
        }
    }

    // ---- d2 partial (per-lane cols are disjoint)
    float d2p = qq_s[0] + qq_s[1] + qq_s[2] + qq_s[3];

    // ---- reduce row stats across 16 lr-lanes
    #pragma unroll
    for (int r = 0; r < 4; ++r) {
        #pragma unroll
        for (int msk = 1; msk <= 8; msk <<= 1) {
            l4[r]   += __shfl_xor(l4[r],   msk);
            sc_s[r] += __shfl_xor(sc_s[r], msk);
            qq_c[r] += __shfl_xor(qq_c[r], msk);
            ss_s[r] += __shfl_xor(ss_s[r], msk);
            qq_s[r] += __shfl_xor(qq_s[r], msk);
        }
    }

    // ---- outputs
    #pragma unroll
    for (int r = 0; r < 4; ++r) {
        float linv = 1.0f / l4[r];
        int row = q0 + wid*16 + lg*4 + r;
        #pragma unroll
        for (int n = 0; n < 4; ++n) {
            int d = n*16 + lr;
            ctx [(((size_t)b*T_ + row)*NH_ + h)*64 + d] = Oc[n][r] * linv;
            out2[((size_t)bh*T_ + row)*64 + d]          = Os[n][r] * linv;
        }
    }

    // ---- row-std ratios (rows replicated on 16 lanes -> 1/16 weight)
    float rp = 0.f;
    #pragma unroll
    for (int r = 0; r < 4; ++r) {
        float S1c = 0.125f    * sc_s[r];
        float S2c = 0.015625f * qq_c[r];
        float S1s = 0.125f    * ss_s[r];
        float S2s = 0.015625f * qq_s[r];
        float varc = (S2c - S1c*S1c*(1.f/1024.f)) * (1.f/1023.f);
        float vars = (S2s - S1s*S1s*(1.f/1024.f)) * (1.f/1023.f);
        rp += sqrtf(fmaxf(vars, 0.f)) / (sqrtf(fmaxf(varc, 0.f)) + 1e-6f);
    }
    rp *= (1.f/16.f);

    #pragma unroll
    for (int msk = 1; msk <= 32; msk <<= 1) {
        d2p += __shfl_xor(d2p, msk);
        rp  += __shfl_xor(rp,  msk);
    }
    __syncthreads();                      // all waves done with LDS
    float* sred = (float*)sP;
    if (lane == 0) { sred[wid] = d2p; sred[4+wid] = rp; }
    __syncthreads();
    if (tid == 0) {
        float td2 = (sred[0]+sred[1]+sred[2]+sred[3]) * coef * coef * 0.015625f;
        float tr  =  sred[4]+sred[5]+sred[6]+sred[7];
        atomicAdd(&accum[0], td2);
        atomicAdd(&accum[1], tr);
    }
}

// ---------------------------------------------------------------- finalize scalars
__global__ void k_fin(const float* __restrict__ acc, float* __restrict__ out) {
    if (threadIdx.x == 0) {
        out[0] = sqrtf(acc[0] * (1.f/67108864.f));   // / (B*NH*T*T)
        out[1] = acc[1] * (1.f/65536.f);             // / (B*NH*T)
    }
}

extern "C" void kernel_launch(void* const* d_in, const int* in_sizes, int n_in,
                              void* d_out, int out_size, void* d_ws, size_t ws_size,
                              hipStream_t stream)
{
    const float* data  = (const float*)d_in[0];
    const float* sin_  = (const float*)d_in[1];
    const float* qkv_w = (const float*)d_in[2];
    const float* qkv_b = (const float*)d_in[3];
    const float* out_w = (const float*)d_in[4];
    const float* out_b = (const float*)d_in[5];
    const float* Wq    = (const float*)d_in[6];
    const float* Wk    = (const float*)d_in[7];
    const float* Wv    = (const float*)d_in[8];
    const float* lam   = (const float*)d_in[9];
    const float* phv   = (const float*)d_in[10];
    float* out = (float*)d_out;
    char*  w   = (char*)d_ws;

    const size_t SZ = (size_t)MSZ * 2;   // 8 MB per bf16 tensor
    __bf16* Qcb  = (__bf16*)(w);
    __bf16* Kcb  = (__bf16*)(w + SZ);
    __bf16* Vtb  = (__bf16*)(w + 2*SZ);
    __bf16* Qsb  = (__bf16*)(w + 3*SZ);
    __bf16* Ksb  = (__bf16*)(w + 4*SZ);
    __bf16* Vstb = (__bf16*)(w + 5*SZ);
    float*  ctx  = (float*)(w + 6*SZ);          // 16 MB
    float*  accum= (float*)(w + 6*SZ + (size_t)MSZ*4);

    k_zero   <<<1, 64, 0, stream>>>(accum);
    k_gemm<0><<<dim3(24, 32), 256, 0, stream>>>(data, qkv_w, qkv_b, Qcb, Kcb, Vtb, nullptr);
    k_sproj  <<<dim3(8, 64), 256, 0, stream>>>(sin_, Wq, Wk, Wv, Qsb, Ksb, Vstb);
    k_attn   <<<dim3(64, 16), 256, 0, stream>>>(Qcb, Kcb, Vtb, Qsb, Ksb, Vstb, lam, phv,
                                                ctx, out + (size_t)MSZ, accum);
    k_gemm<1><<<dim3(8, 32), 256, 0, stream>>>(ctx, out_w, out_b, nullptr, nullptr, nullptr, out);
    k_fin    <<<1, 64, 0, stream>>>(accum, out + 2*(size_t)MSZ);
}

// Round 6
// 357.777 us; speedup vs baseline: 3.7471x; 1.3935x over previous
//
#include <hip/hip_runtime.h>
#include <math.h>
#include <stdint.h>

#define B_ 4
#define T_ 1024
#define NH_ 16
#define MSZ (4194304)   // B*T*1024 elems

typedef float f4 __attribute__((ext_vector_type(4)));
typedef float f32x4 __attribute__((ext_vector_type(4)));
typedef __bf16 bf16x8 __attribute__((ext_vector_type(8)));
typedef __bf16 bf16x4 __attribute__((ext_vector_type(4)));

static __device__ __forceinline__ f32x4 mfma16(bf16x8 a, bf16x8 b, f32x4 c) {
    return __builtin_amdgcn_mfma_f32_16x16x32_bf16(a, b, c, 0, 0, 0);
}

// global -> LDS direct 16B copy (lane l writes dst + l*16)
static __device__ __forceinline__ void gld16(const void* g, void* l) {
    auto gp = reinterpret_cast<const uint32_t __attribute__((address_space(1)))*>(
        reinterpret_cast<uintptr_t>(g));
    auto lp = reinterpret_cast<uint32_t __attribute__((address_space(3)))*>(
        reinterpret_cast<uintptr_t>(l));
    __builtin_amdgcn_global_load_lds(gp, lp, 16, 0, 0);
}

// ---------------------------------------------------------------- zero accum
__global__ void k_zero(float* acc) {
    if (threadIdx.x < 2) acc[threadIdx.x] = 0.f;
}

// ---------------------------------------------------------------- hi/lo bf16 split of f32 inputs
// ranges (f4 units): data 1048576 | qkv_w 786432 | out_w 262144  -> total 2097152
__global__ __launch_bounds__(256) void k_split(
        const float* __restrict__ data, __bf16* __restrict__ dH, __bf16* __restrict__ dL,
        const float* __restrict__ w1,   __bf16* __restrict__ w1H, __bf16* __restrict__ w1L,
        const float* __restrict__ w2,   __bf16* __restrict__ w2H, __bf16* __restrict__ w2L)
{
    const int gsz = gridDim.x * blockDim.x;
    for (size_t i = blockIdx.x * blockDim.x + threadIdx.x; i < 2097152; i += gsz) {
        const float* s; __bf16 *H, *L; size_t off;
        if (i < 1048576)      { s = data; H = dH;  L = dL;  off = i; }
        else if (i < 1835008) { s = w1;   H = w1H; L = w1L; off = i - 1048576; }
        else                  { s = w2;   H = w2H; L = w2L; off = i - 1835008; }
        f4 v = *(const f4*)(s + off*4);
        bf16x4 h, l;
        #pragma unroll
        for (int j = 0; j < 4; ++j) {
            __bf16 hh = (__bf16)v[j];
            h[j] = hh;
            l[j] = (__bf16)(v[j] - (float)hh);
        }
        *(bf16x4*)(H + off*4) = h;
        *(bf16x4*)(L + off*4) = l;
    }
}

// ---------------------------------------------------------------- split-bf16 MFMA GEMM
// C[n,m] = sum_k A[n,k]*W[m,k] + bias[m]; A,W given as hi/lo bf16 pairs [rows][1024].
// 3 MFMA passes: al*bh + ah*bl + ah*bh. Staging via global_load_lds (pre-swizzled src).
// MODE 0 (qkv): M=3072, outputs bf16 Qb/Kb ([bh][t][64]) and Vtb ([bh][d][t]).
// MODE 1 (oproj): M=1024, output f32 [n][m].
template<int MODE>
__global__ __launch_bounds__(256, 2) void k_gemm(
        const __bf16* __restrict__ AH, const __bf16* __restrict__ AL,
        const __bf16* __restrict__ BH, const __bf16* __restrict__ BL,
        const float* __restrict__ bias,
        __bf16* __restrict__ Qb, __bf16* __restrict__ Kb, __bf16* __restrict__ Vtb,
        float* __restrict__ outf)
{
    __shared__ __bf16 sAH[8192];   // [128 rows][64 bf16 = 128B], chunk-XOR swizzled
    __shared__ __bf16 sAL[8192];
    __shared__ __bf16 sBH[8192];
    __shared__ __bf16 sBL[8192];

    const int tid  = threadIdx.x;
    const int lane = tid & 63;
    const int wid  = tid >> 6;
    const int lr   = lane & 15;
    const int lg   = lane >> 4;
    const int wr   = wid >> 1, wc = wid & 1;
    const int m0 = blockIdx.x * 128;
    const int n0 = blockIdx.y * 128;

    f32x4 acc[4][4];
    #pragma unroll
    for (int i = 0; i < 4; ++i)
        #pragma unroll
        for (int j = 0; j < 4; ++j) acc[i][j] = (f32x4){0.f,0.f,0.f,0.f};

    const int rbase = wid * 32;               // 32 tile-rows staged per wave
    const int srow8 = lane >> 3;              // 8 rows per gld16 call
    const int schnk = lane & 7;

    for (int k0 = 0; k0 < 1024; k0 += 64) {
        __syncthreads();
        #pragma unroll
        for (int c = 0; c < 4; ++c) {
            int row = rbase + c*8 + srow8;
            size_t sc_ = (size_t)((schnk ^ (row & 7)) << 4);
            size_t dst = (size_t)(rbase + c*8) * 128;
            size_t asrc = (size_t)(n0 + row) * 2048 + (size_t)k0*2 + sc_;
            size_t bsrc = (size_t)(m0 + row) * 2048 + (size_t)k0*2 + sc_;
            gld16((const char*)AH + asrc, (char*)sAH + dst);
            gld16((const char*)AL + asrc, (char*)sAL + dst);
            gld16((const char*)BH + bsrc, (char*)sBH + dst);
            gld16((const char*)BL + bsrc, (char*)sBL + dst);
        }
        __syncthreads();

        #pragma unroll
        for (int kk = 0; kk < 2; ++kk) {
            bf16x8 ah[4], al[4], bh_[4], bl[4];
            #pragma unroll
            for (int rf = 0; rf < 4; ++rf) {
                int row = wr*64 + rf*16 + lr;
                int byte = row*128 + (((kk*4 + lg) ^ (row & 7)) << 4);
                ah[rf] = *(const bf16x8*)((const char*)sAH + byte);
                al[rf] = *(const bf16x8*)((const char*)sAL + byte);
            }
            #pragma unroll
            for (int n = 0; n < 4; ++n) {
                int row = wc*64 + n*16 + lr;
                int byte = row*128 + (((kk*4 + lg) ^ (row & 7)) << 4);
                bh_[n] = *(const bf16x8*)((const char*)sBH + byte);
                bl[n]  = *(const bf16x8*)((const char*)sBL + byte);
            }
            #pragma unroll
            for (int rf = 0; rf < 4; ++rf)
                #pragma unroll
                for (int n = 0; n < 4; ++n) {
                    acc[rf][n] = mfma16(al[rf], bh_[n], acc[rf][n]);
                    acc[rf][n] = mfma16(ah[rf], bl[n],  acc[rf][n]);
                    acc[rf][n] = mfma16(ah[rf], bh_[n], acc[rf][n]);
                }
        }
    }

    // epilogue
    #pragma unroll
    for (int n = 0; n < 4; ++n) {
        int col = m0 + wc*64 + n*16 + lr;
        float bb = bias[col];
        #pragma unroll
        for (int rf = 0; rf < 4; ++rf)
            #pragma unroll
            for (int r = 0; r < 4; ++r) {
                float v = acc[rf][n][r] + bb;
                int trow = n0 + wr*64 + rf*16 + lg*4 + r;
                if (MODE == 1) {
                    outf[(size_t)trow*1024 + col] = v;
                } else {
                    int js = col >> 10;
                    int hh = (col >> 6) & 15;
                    int dd = col & 63;
                    int b  = trow >> 10, t = trow & 1023;
                    int bh = b*16 + hh;
                    __bf16 bv = (__bf16)v;
                    if (js == 0)      Qb [((size_t)bh*1024 + t)*64 + dd] = bv;
                    else if (js == 1) Kb [((size_t)bh*1024 + t)*64 + dd] = bv;
                    else              Vtb[((size_t)bh*64 + dd)*1024 + t] = bv;
                }
            }
    }
}

// ---------------------------------------------------------------- scratch projections (f32 math, bf16 out)
__global__ __launch_bounds__(256) void k_sproj(const float* __restrict__ sin_,
        const float* __restrict__ Wq, const float* __restrict__ Wk, const float* __restrict__ Wv,
        __bf16* __restrict__ Qsb, __bf16* __restrict__ Ksb, __bf16* __restrict__ Vstb)
{
    __shared__ float inT[64*132];
    __shared__ float Wt[64*68];
    const int tid = threadIdx.x;
    const int tx = tid & 15, ty = tid >> 4;
    const int bh = blockIdx.y;
    const int h  = bh & (NH_-1);
    const int t0 = blockIdx.x * 128;
    const size_t base = ((size_t)bh * T_ + t0) * 64;

    #pragma unroll
    for (int l = 0; l < 8; ++l) {
        int fid = l*256 + tid;
        int row = fid >> 4, c4 = fid & 15;
        f4 a = *(const f4*)&sin_[base + (size_t)row*64 + c4*4];
        #pragma unroll
        for (int j = 0; j < 4; ++j) inT[(c4*4+j)*132 + row] = a[j];
    }

    for (int w = 0; w < 3; ++w) {
        const float* Wp = (w == 0) ? Wq : ((w == 1) ? Wk : Wv);
        __syncthreads();
        #pragma unroll
        for (int l = 0; l < 4; ++l) {
            int fid = l*256 + tid;
            int s = fid >> 4, c4 = fid & 15;
            *(f4*)&Wt[s*68 + c4*4] = *(const f4*)&Wp[(size_t)h*4096 + s*64 + c4*4];
        }
        __syncthreads();
        float acc[8][4] = {};
        #pragma unroll 8
        for (int s = 0; s < 64; ++s) {
            f4 w4 = *(const f4*)&Wt[s*68 + tx*4];
            f4 a0 = *(const f4*)&inT[s*132 + ty*8];
            f4 a1 = *(const f4*)&inT[s*132 + ty*8 + 4];
            #pragma unroll
            for (int r = 0; r < 4; ++r)
                #pragma unroll
                for (int j = 0; j < 4; ++j) {
                    acc[r][j]   += a0[r]*w4[j];
                    acc[4+r][j] += a1[r]*w4[j];
                }
        }
        if (w < 2) {
            __bf16* Op = (w == 0) ? Qsb : Ksb;
            #pragma unroll
            for (int r = 0; r < 8; ++r) {
                bf16x4 v;
                #pragma unroll
                for (int j = 0; j < 4; ++j) v[j] = (__bf16)acc[r][j];
                *(bf16x4*)&Op[base + (size_t)(ty*8+r)*64 + tx*4] = v;
            }
        } else {
            #pragma unroll
            for (int r = 0; r < 8; ++r)
                #pragma unroll
                for (int j = 0; j < 4; ++j)
                    Vstb[((size_t)bh*64 + tx*4+j)*1024 + t0 + ty*8 + r] = (__bf16)acc[r][j];
        }
    }
}

// ---------------------------------------------------------------- MFMA flash attention + stats
// QTILE=64 (4 waves x 16 rows), KTILE=64. All operands bf16 in global.
// K/Ks row-major [key][64]; V/Vs pre-transposed [d][t]. LDS staged via global_load_lds
// with inverse-swizzled source; reads use chunk-XOR swizzle (chunk ^= row&7).
// Epilogue: ctx emitted as hi/lo bf16 split for the oproj GEMM.
__global__ __launch_bounds__(256, 3) void k_attn(
        const __bf16* __restrict__ Qcb, const __bf16* __restrict__ Kcb, const __bf16* __restrict__ Vtb,
        const __bf16* __restrict__ Qsb, const __bf16* __restrict__ Ksb, const __bf16* __restrict__ Vstb,
        const float* __restrict__ lam, const float* __restrict__ phv,
        __bf16* __restrict__ ctxH, __bf16* __restrict__ ctxL,
        float* __restrict__ out2, float* __restrict__ accum)
{
    __shared__ __bf16 sKC[4096];   // [64 key][64 d]
    __shared__ __bf16 sKS[4096];
    __shared__ __bf16 sVC[4096];   // [64 d][64 key]  (from Vtb)
    __shared__ __bf16 sVS[4096];
    __shared__ __bf16 sP [4096];   // [64 qrow][64 key], wave-local strips

    const int tid  = threadIdx.x;
    const int lane = tid & 63;
    const int wid  = tid >> 6;
    const int lr   = lane & 15;
    const int lg   = lane >> 4;
    const int bh   = blockIdx.x;          // 0..63
    const int qt   = 15 - blockIdx.y;     // reversed: heavy blocks first
    const int h    = bh & (NH_-1);
    const int b    = bh >> 4;
    const int q0   = qt * 64;

    const float lv   = lam[0];
    const float coef = (lv > 1e-8f ? lv : 0.f) * __expf(phv[h]);

    // Q fragments direct from global bf16
    bf16x8 qcf[2], qsf[2];
    {
        int row = q0 + wid*16 + lr;
        size_t qb = ((size_t)bh*1024 + row)*64;
        #pragma unroll
        for (int hf = 0; hf < 2; ++hf) {
            qcf[hf] = *(const bf16x8*)&Qcb[qb + hf*32 + lg*8];
            qsf[hf] = *(const bf16x8*)&Qsb[qb + hf*32 + lg*8];
        }
    }

    f32x4 Oc[4], Os[4];
    #pragma unroll
    for (int n = 0; n < 4; ++n) { Oc[n] = (f32x4){0,0,0,0}; Os[n] = (f32x4){0,0,0,0}; }

    float m4[4], l4[4];
    float sc_s[4] = {}, qq_c[4] = {}, ss_s[4] = {}, qq_s[4] = {};
    #pragma unroll
    for (int i = 0; i < 4; ++i) { m4[i] = -INFINITY; l4[i] = 0.f; }

    const char* kcB = (const char*)Kcb  + (size_t)bh*1024*128;
    const char* ksB = (const char*)Ksb  + (size_t)bh*1024*128;
    const char* vtB = (const char*)Vtb  + (size_t)bh*64*2048;
    const char* vsB = (const char*)Vstb + (size_t)bh*64*2048;

    for (int kt = 0; kt < 16; ++kt) {
        const bool pv = (kt <= qt);
        __syncthreads();
        // ---- stage via global_load_lds (each wave: 2 x 1KB per tile)
        #pragma unroll
        for (int c = 0; c < 2; ++c) {
            int trow = wid*16 + c*8 + (lane>>3);
            int sc_  = (lane&7) ^ (trow&7);
            size_t dsto = (size_t)wid*2048 + c*1024;
            gld16(kcB + ((size_t)(kt*64 + trow))*128 + sc_*16, (char*)sKC + dsto);
            gld16(ksB + ((size_t)(kt*64 + trow))*128 + sc_*16, (char*)sKS + dsto);
            if (pv) {
                gld16(vtB + (size_t)trow*2048 + kt*128 + sc_*16, (char*)sVC + dsto);
                gld16(vsB + (size_t)trow*2048 + kt*128 + sc_*16, (char*)sVS + dsto);
            }
        }
        __syncthreads();

        // ---- S = Q K^T both streams + stats
        float L[4][4];   // [n][r]
        #pragma unroll
        for (int n = 0; n < 4; ++n) {
            int krow = n*16 + lr;
            int rswz = krow & 7;
            const char* pc = (const char*)sKC + krow*128;
            const char* ps = (const char*)sKS + krow*128;
            bf16x8 kc0 = *(const bf16x8*)(pc + (((lg  ) ^ rswz)<<4));
            bf16x8 kc1 = *(const bf16x8*)(pc + (((lg+4) ^ rswz)<<4));
            bf16x8 ks0 = *(const bf16x8*)(ps + (((lg  ) ^ rswz)<<4));
            bf16x8 ks1 = *(const bf16x8*)(ps + (((lg+4) ^ rswz)<<4));
            f32x4 z = {0.f,0.f,0.f,0.f};
            f32x4 sc = mfma16(qcf[1], kc1, mfma16(qcf[0], kc0, z));
            f32x4 ss = mfma16(qsf[1], ks1, mfma16(qsf[0], ks0, z));
            #pragma unroll
            for (int r = 0; r < 4; ++r) {
                sc_s[r] += sc[r];
                qq_c[r] = fmaf(sc[r], sc[r], qq_c[r]);
                ss_s[r] += ss[r];
                qq_s[r] = fmaf(ss[r], ss[r], qq_s[r]);
                L[n][r] = 0.125f * fmaf(coef, ss[r], sc[r]);
            }
        }
        if (!pv) continue;

        // ---- causal mask on diagonal tile
        if (kt == qt) {
            #pragma unroll
            for (int n = 0; n < 4; ++n) {
                int kc = n*16 + lr;
                #pragma unroll
                for (int r = 0; r < 4; ++r)
                    if (kc > wid*16 + lg*4 + r) L[n][r] = -INFINITY;
            }
        }

        // ---- online softmax (rows = lg*4+r, cols split across 16 lr-lanes)
        float fr4[4];
        #pragma unroll
        for (int r = 0; r < 4; ++r) {
            float v = fmaxf(fmaxf(L[0][r], L[1][r]), fmaxf(L[2][r], L[3][r]));
            v = fmaxf(v, __shfl_xor(v, 1));
            v = fmaxf(v, __shfl_xor(v, 2));
            v = fmaxf(v, __shfl_xor(v, 4));
            v = fmaxf(v, __shfl_xor(v, 8));
            float mn = fmaxf(m4[r], v);
            float fr = __expf(m4[r] - mn);
            m4[r] = mn; fr4[r] = fr;
            float ps = 0.f;
            #pragma unroll
            for (int n = 0; n < 4; ++n) {
                float p = __expf(L[n][r] - mn);
                L[n][r] = p;
                ps += p;
            }
            l4[r] = l4[r]*fr + ps;
        }
        #pragma unroll
        for (int n = 0; n < 4; ++n)
            #pragma unroll
            for (int r = 0; r < 4; ++r) {
                Oc[n][r] *= fr4[r];
                Os[n][r] *= fr4[r];
            }

        // ---- P -> wave-local LDS strip (bf16, swizzled)
        #pragma unroll
        for (int n = 0; n < 4; ++n)
            #pragma unroll
            for (int r = 0; r < 4; ++r) {
                int prow = wid*16 + lg*4 + r;
                *((__bf16*)((char*)sP + prow*128 + ((((n*16+lr)>>3) ^ (prow&7))<<4) + (((n*16+lr)&7)<<1))) = (__bf16)L[n][r];
            }

        // ---- O += P V (both streams)
        bf16x8 pa[2];
        {
            int prow = wid*16 + lr;
            const char* pp = (const char*)sP + prow*128;
            pa[0] = *(const bf16x8*)(pp + (((lg  ) ^ (prow&7))<<4));
            pa[1] = *(const bf16x8*)(pp + (((lg+4) ^ (prow&7))<<4));
        }
        #pragma unroll
        for (int n = 0; n < 4; ++n) {
            int vrow = n*16 + lr;
            int rswz = vrow & 7;
            const char* pc = (const char*)sVC + vrow*128;
            const char* ps = (const char*)sVS + vrow*128;
            bf16x8 vc0 = *(const bf16x8*)(pc + (((lg  ) ^ rswz)<<4));
            bf16x8 vc1 = *(const bf16x8*)(pc + (((lg+4) ^ rswz)<<4));
            bf16x8 vs0 = *(const bf16x8*)(ps + (((lg  ) ^ rswz)<<4));
            bf16x8 vs1 = *(const bf16x8*)(ps + (((lg+4) ^ rswz)<<4));
            Oc[n] = mfma16(pa[1], vc1, mfma16(pa[0], vc0, Oc[n]));
            Os[n] = mfma16(pa[1], vs1, mfma16(pa[0], vs0, Os[n]));
        }
    }

    // ---- d2 partial (per-lane cols are disjoint)
    float d2p = qq_s[0] + qq_s[1] + qq_s[2] + qq_s[3];

    // ---- reduce row stats across 16 lr-lanes
    #pragma unroll
    for (int r = 0; r < 4; ++r) {
        #pragma unroll
        for (int msk = 1; msk <= 8; msk <<= 1) {
            l4[r]   += __shfl_xor(l4[r],   msk);
            sc_s[r] += __shfl_xor(sc_s[r], msk);
            qq_c[r] += __shfl_xor(qq_c[r], msk);
            ss_s[r] += __shfl_xor(ss_s[r], msk);
            qq_s[r] += __shfl_xor(qq_s[r], msk);
        }
    }

    // ---- outputs (ctx as hi/lo bf16 split; out2 f32)
    #pragma unroll
    for (int r = 0; r < 4; ++r) {
        float linv = 1.0f / l4[r];
        int row = q0 + wid*16 + lg*4 + r;
        #pragma unroll
        for (int n = 0; n < 4; ++n) {
            int d = n*16 + lr;
            float oc = Oc[n][r] * linv;
            size_t cidx = (((size_t)b*T_ + row)*NH_ + h)*64 + d;
            __bf16 hv = (__bf16)oc;
            ctxH[cidx] = hv;
            ctxL[cidx] = (__bf16)(oc - (float)hv);
            out2[((size_t)bh*T_ + row)*64 + d] = Os[n][r] * linv;
        }
    }

    // ---- row-std ratios (rows replicated on 16 lanes -> 1/16 weight)
    float rp = 0.f;
    #pragma unroll
    for (int r = 0; r < 4; ++r) {
        float S1c = 0.125f    * sc_s[r];
        float S2c = 0.015625f * qq_c[r];
        float S1s = 0.125f    * ss_s[r];
        float S2s = 0.015625f * qq_s[r];
        float varc = (S2c - S1c*S1c*(1.f/1024.f)) * (1.f/1023.f);
        float vars = (S2s - S1s*S1s*(1.f/1024.f)) * (1.f/1023.f);
        rp += sqrtf(fmaxf(vars, 0.f)) / (sqrtf(fmaxf(varc, 0.f)) + 1e-6f);
    }
    rp *= (1.f/16.f);

    #pragma unroll
    for (int msk = 1; msk <= 32; msk <<= 1) {
        d2p += __shfl_xor(d2p, msk);
        rp  += __shfl_xor(rp,  msk);
    }
    __syncthreads();                      // all waves done with LDS
    float* sred = (float*)sP;
    if (lane == 0) { sred[wid] = d2p; sred[4+wid] = rp; }
    __syncthreads();
    if (tid == 0) {
        float td2 = (sred[0]+sred[1]+sred[2]+sred[3]) * coef * coef * 0.015625f;
        float tr  =  sred[4]+sred[5]+sred[6]+sred[7];
        atomicAdd(&accum[0], td2);
        atomicAdd(&accum[1], tr);
    }
}

// ---------------------------------------------------------------- finalize scalars
__global__ void k_fin(const float* __restrict__ acc, float* __restrict__ out) {
    if (threadIdx.x == 0) {
        out[0] = sqrtf(acc[0] * (1.f/67108864.f));   // / (B*NH*T*T)
        out[1] = acc[1] * (1.f/65536.f);             // / (B*NH*T)
    }
}

extern "C" void kernel_launch(void* const* d_in, const int* in_sizes, int n_in,
                              void* d_out, int out_size, void* d_ws, size_t ws_size,
                              hipStream_t stream)
{
    const float* data  = (const float*)d_in[0];
    const float* sin_  = (const float*)d_in[1];
    const float* qkv_w = (const float*)d_in[2];
    const float* qkv_b = (const float*)d_in[3];
    const float* out_w = (const float*)d_in[4];
    const float* out_b = (const float*)d_in[5];
    const float* Wq    = (const float*)d_in[6];
    const float* Wk    = (const float*)d_in[7];
    const float* Wv    = (const float*)d_in[8];
    const float* lam   = (const float*)d_in[9];
    const float* phv   = (const float*)d_in[10];
    float* out = (float*)d_out;
    char*  w   = (char*)d_ws;

    const size_t MB = 1024*1024;
    __bf16* Qcb   = (__bf16*)(w);             // 8 MB each
    __bf16* Kcb   = (__bf16*)(w + 8*MB);
    __bf16* Vtb   = (__bf16*)(w + 16*MB);
    __bf16* Qsb   = (__bf16*)(w + 24*MB);
    __bf16* Ksb   = (__bf16*)(w + 32*MB);
    __bf16* Vstb  = (__bf16*)(w + 40*MB);
    __bf16* dataH = (__bf16*)(w + 48*MB);     // aliased as ctxH after qkv GEMM
    __bf16* dataL = (__bf16*)(w + 56*MB);     // aliased as ctxL
    __bf16* wH    = (__bf16*)(w + 64*MB);     // 6 MB each
    __bf16* wL    = (__bf16*)(w + 70*MB);
    __bf16* owH   = (__bf16*)(w + 76*MB);     // 2 MB each
    __bf16* owL   = (__bf16*)(w + 78*MB);
    float*  accum = (float*)(w + 80*MB);

    k_zero   <<<1, 64, 0, stream>>>(accum);
    k_split  <<<2048, 256, 0, stream>>>(data, dataH, dataL, qkv_w, wH, wL, out_w, owH, owL);
    k_gemm<0><<<dim3(24, 32), 256, 0, stream>>>(dataH, dataL, wH, wL, qkv_b, Qcb, Kcb, Vtb, nullptr);
    k_sproj  <<<dim3(8, 64), 256, 0, stream>>>(sin_, Wq, Wk, Wv, Qsb, Ksb, Vstb);
    k_attn   <<<dim3(64, 16), 256, 0, stream>>>(Qcb, Kcb, Vtb, Qsb, Ksb, Vstb, lam, phv,
                                                dataH, dataL, out + (size_t)MSZ, accum);
    k_gemm<1><<<dim3(8, 32), 256, 0, stream>>>(dataH, dataL, owH, owL, out_b, nullptr, nullptr, nullptr, out);
    k_fin    <<<1, 64, 0, stream>>>(accum, out + 2*(size_t)MSZ);
}

// Round 8
// 329.194 us; speedup vs baseline: 4.0725x; 1.0868x over previous
//
#include <hip/hip_runtime.h>
#include <math.h>
#include <stdint.h>

#define B_ 4
#define T_ 1024
#define NH_ 16
#define MSZ (4194304)   // B*T*1024 elems

typedef float f4 __attribute__((ext_vector_type(4)));
typedef float f32x4 __attribute__((ext_vector_type(4)));
typedef __bf16 bf16x8 __attribute__((ext_vector_type(8)));
typedef __bf16 bf16x4 __attribute__((ext_vector_type(4)));

static __device__ __forceinline__ f32x4 mfma16(bf16x8 a, bf16x8 b, f32x4 c) {
    return __builtin_amdgcn_mfma_f32_16x16x32_bf16(a, b, c, 0, 0, 0);
}

// global -> LDS direct 16B copy (lane l writes dst + l*16)
static __device__ __forceinline__ void gld16(const void* g, void* l) {
    auto gp = reinterpret_cast<const uint32_t __attribute__((address_space(1)))*>(
        reinterpret_cast<uintptr_t>(g));
    auto lp = reinterpret_cast<uint32_t __attribute__((address_space(3)))*>(
        reinterpret_cast<uintptr_t>(l));
    __builtin_amdgcn_global_load_lds(gp, lp, 16, 0, 0);
}

// ---------------------------------------------------------------- zero accum
__global__ void k_zero(float* acc) {
    if (threadIdx.x < 2) acc[threadIdx.x] = 0.f;
}

// ---------------------------------------------------------------- hi/lo bf16 split of f32 inputs
// ranges (f4 units): data 1048576 | qkv_w 786432 | out_w 262144  -> total 2097152
__global__ __launch_bounds__(256) void k_split(
        const float* __restrict__ data, __bf16* __restrict__ dH, __bf16* __restrict__ dL,
        const float* __restrict__ w1,   __bf16* __restrict__ w1H, __bf16* __restrict__ w1L,
        const float* __restrict__ w2,   __bf16* __restrict__ w2H, __bf16* __restrict__ w2L)
{
    const int gsz = gridDim.x * blockDim.x;
    for (size_t i = blockIdx.x * blockDim.x + threadIdx.x; i < 2097152; i += gsz) {
        const float* s; __bf16 *H, *L; size_t off;
        if (i < 1048576)      { s = data; H = dH;  L = dL;  off = i; }
        else if (i < 1835008) { s = w1;   H = w1H; L = w1L; off = i - 1048576; }
        else                  { s = w2;   H = w2H; L = w2L; off = i - 1835008; }
        f4 v = *(const f4*)(s + off*4);
        bf16x4 h, l;
        #pragma unroll
        for (int j = 0; j < 4; ++j) {
            __bf16 hh = (__bf16)v[j];
            h[j] = hh;
            l[j] = (__bf16)(v[j] - (float)hh);
        }
        *(bf16x4*)(H + off*4) = h;
        *(bf16x4*)(L + off*4) = l;
    }
}

// ---------------------------------------------------------------- split-bf16 MFMA GEMM
// C[n,m] = sum_k A[n,k]*W[m,k] + bias[m]; A,W given as hi/lo bf16 pairs [rows][1024].
// 3 MFMA passes: al*bh + ah*bl + ah*bh. Staging via global_load_lds (pre-swizzled src).
// MODE 0 (qkv): M=3072, outputs bf16 Qb/Kb ([bh][t][64]) and Vtb ([bh][d][t]).
// MODE 1 (oproj): M=1024, output f32 [n][m].
template<int MODE>
__global__ __launch_bounds__(256, 2) void k_gemm(
        const __bf16* __restrict__ AH, const __bf16* __restrict__ AL,
        const __bf16* __restrict__ BH, const __bf16* __restrict__ BL,
        const float* __restrict__ bias,
        __bf16* __restrict__ Qb, __bf16* __restrict__ Kb, __bf16* __restrict__ Vtb,
        float* __restrict__ outf)
{
    __shared__ __bf16 sAH[8192];   // [128 rows][64 bf16 = 128B], chunk-XOR swizzled
    __shared__ __bf16 sAL[8192];
    __shared__ __bf16 sBH[8192];
    __shared__ __bf16 sBL[8192];

    const int tid  = threadIdx.x;
    const int lane = tid & 63;
    const int wid  = tid >> 6;
    const int lr   = lane & 15;
    const int lg   = lane >> 4;
    const int wr   = wid >> 1, wc = wid & 1;
    const int m0 = blockIdx.x * 128;
    const int n0 = blockIdx.y * 128;

    f32x4 acc[4][4];
    #pragma unroll
    for (int i = 0; i < 4; ++i)
        #pragma unroll
        for (int j = 0; j < 4; ++j) acc[i][j] = (f32x4){0.f,0.f,0.f,0.f};

    const int rbase = wid * 32;               // 32 tile-rows staged per wave
    const int srow8 = lane >> 3;              // 8 rows per gld16 call
    const int schnk = lane & 7;

    for (int k0 = 0; k0 < 1024; k0 += 64) {
        __syncthreads();
        #pragma unroll
        for (int c = 0; c < 4; ++c) {
            int row = rbase + c*8 + srow8;
            size_t sc_ = (size_t)((schnk ^ (row & 7)) << 4);
            size_t dst = (size_t)(rbase + c*8) * 128;
            size_t asrc = (size_t)(n0 + row) * 2048 + (size_t)k0*2 + sc_;
            size_t bsrc = (size_t)(m0 + row) * 2048 + (size_t)k0*2 + sc_;
            gld16((const char*)AH + asrc, (char*)sAH + dst);
            gld16((const char*)AL + asrc, (char*)sAL + dst);
            gld16((const char*)BH + bsrc, (char*)sBH + dst);
            gld16((const char*)BL + bsrc, (char*)sBL + dst);
        }
        __syncthreads();

        #pragma unroll
        for (int kk = 0; kk < 2; ++kk) {
            bf16x8 ah[4], al[4], bh_[4], bl[4];
            #pragma unroll
            for (int rf = 0; rf < 4; ++rf) {
                int row = wr*64 + rf*16 + lr;
                int byte = row*128 + (((kk*4 + lg) ^ (row & 7)) << 4);
                ah[rf] = *(const bf16x8*)((const char*)sAH + byte);
                al[rf] = *(const bf16x8*)((const char*)sAL + byte);
            }
            #pragma unroll
            for (int n = 0; n < 4; ++n) {
                int row = wc*64 + n*16 + lr;
                int byte = row*128 + (((kk*4 + lg) ^ (row & 7)) << 4);
                bh_[n] = *(const bf16x8*)((const char*)sBH + byte);
                bl[n]  = *(const bf16x8*)((const char*)sBL + byte);
            }
            #pragma unroll
            for (int rf = 0; rf < 4; ++rf)
                #pragma unroll
                for (int n = 0; n < 4; ++n) {
                    acc[rf][n] = mfma16(al[rf], bh_[n], acc[rf][n]);
                    acc[rf][n] = mfma16(ah[rf], bl[n],  acc[rf][n]);
                    acc[rf][n] = mfma16(ah[rf], bh_[n], acc[rf][n]);
                }
        }
    }

    // epilogue
    #pragma unroll
    for (int n = 0; n < 4; ++n) {
        int col = m0 + wc*64 + n*16 + lr;
        float bb = bias[col];
        #pragma unroll
        for (int rf = 0; rf < 4; ++rf)
            #pragma unroll
            for (int r = 0; r < 4; ++r) {
                float v = acc[rf][n][r] + bb;
                int trow = n0 + wr*64 + rf*16 + lg*4 + r;
                if (MODE == 1) {
                    outf[(size_t)trow*1024 + col] = v;
                } else {
                    int js = col >> 10;
                    int hh = (col >> 6) & 15;
                    int dd = col & 63;
                    int b  = trow >> 10, t = trow & 1023;
                    int bh = b*16 + hh;
                    __bf16 bv = (__bf16)v;
                    if (js == 0)      Qb [((size_t)bh*1024 + t)*64 + dd] = bv;
                    else if (js == 1) Kb [((size_t)bh*1024 + t)*64 + dd] = bv;
                    else              Vtb[((size_t)bh*64 + dd)*1024 + t] = bv;
                }
            }
    }
}

// ---------------------------------------------------------------- scratch projections (f32 math, bf16 out)
__global__ __launch_bounds__(256) void k_sproj(const float* __restrict__ sin_,
        const float* __restrict__ Wq, const float* __restrict__ Wk, const float* __restrict__ Wv,
        __bf16* __restrict__ Qsb, __bf16* __restrict__ Ksb, __bf16* __restrict__ Vstb)
{
    __shared__ float inT[64*132];
    __shared__ float Wt[64*68];
    const int tid = threadIdx.x;
    const int tx = tid & 15, ty = tid >> 4;
    const int bh = blockIdx.y;
    const int h  = bh & (NH_-1);
    const int t0 = blockIdx.x * 128;
    const size_t base = ((size_t)bh * T_ + t0) * 64;

    #pragma unroll
    for (int l = 0; l < 8; ++l) {
        int fid = l*256 + tid;
        int row = fid >> 4, c4 = fid & 15;
        f4 a = *(const f4*)&sin_[base + (size_t)row*64 + c4*4];
        #pragma unroll
        for (int j = 0; j < 4; ++j) inT[(c4*4+j)*132 + row] = a[j];
    }

    for (int w = 0; w < 3; ++w) {
        const float* Wp = (w == 0) ? Wq : ((w == 1) ? Wk : Wv);
        __syncthreads();
        #pragma unroll
        for (int l = 0; l < 4; ++l) {
            int fid = l*256 + tid;
            int s = fid >> 4, c4 = fid & 15;
            *(f4*)&Wt[s*68 + c4*4] = *(const f4*)&Wp[(size_t)h*4096 + s*64 + c4*4];
        }
        __syncthreads();
        float acc[8][4] = {};
        #pragma unroll 8
        for (int s = 0; s < 64; ++s) {
            f4 w4 = *(const f4*)&Wt[s*68 + tx*4];
            f4 a0 = *(const f4*)&inT[s*132 + ty*8];
            f4 a1 = *(const f4*)&inT[s*132 + ty*8 + 4];
            #pragma unroll
            for (int r = 0; r < 4; ++r)
                #pragma unroll
                for (int j = 0; j < 4; ++j) {
                    acc[r][j]   += a0[r]*w4[j];
                    acc[4+r][j] += a1[r]*w4[j];
                }
        }
        if (w < 2) {
            __bf16* Op = (w == 0) ? Qsb : Ksb;
            #pragma unroll
            for (int r = 0; r < 8; ++r) {
                bf16x4 v;
                #pragma unroll
                for (int j = 0; j < 4; ++j) v[j] = (__bf16)acc[r][j];
                *(bf16x4*)&Op[base + (size_t)(ty*8+r)*64 + tx*4] = v;
            }
        } else {
            #pragma unroll
            for (int r = 0; r < 8; ++r)
                #pragma unroll
                for (int j = 0; j < 4; ++j)
                    Vstb[((size_t)bh*64 + tx*4+j)*1024 + t0 + ty*8 + r] = (__bf16)acc[r][j];
        }
    }
}

// ---------------------------------------------------------------- MFMA flash attention + stats
// QTILE=64 (4 waves x 16 rows), KTILE=64. All operands bf16 in global.
// 2-phase pipeline (T3 minimum): K/Ks/V/Vs double-buffered in LDS; tile t+1's
// global_load_lds issued BEFORE tile t's compute; ONE barrier per tile (its
// implicit vmcnt(0) drain lands after compute has covered the load latency).
__global__ __launch_bounds__(256, 2) void k_attn(
        const __bf16* __restrict__ Qcb, const __bf16* __restrict__ Kcb, const __bf16* __restrict__ Vtb,
        const __bf16* __restrict__ Qsb, const __bf16* __restrict__ Ksb, const __bf16* __restrict__ Vstb,
        const float* __restrict__ lam, const float* __restrict__ phv,
        __bf16* __restrict__ ctxH, __bf16* __restrict__ ctxL,
        float* __restrict__ out2, float* __restrict__ accum)
{
    __shared__ __bf16 sKC[2][4096];   // [64 key][64 d], chunk-XOR swizzled
    __shared__ __bf16 sKS[2][4096];
    __shared__ __bf16 sVC[2][4096];   // [64 d][64 key]  (from Vtb)
    __shared__ __bf16 sVS[2][4096];
    __shared__ __bf16 sP [4096];      // [64 qrow][64 key], wave-local strips

    const int tid  = threadIdx.x;
    const int lane = tid & 63;
    const int wid  = tid >> 6;
    const int lr   = lane & 15;
    const int lg   = lane >> 4;
    const int bh   = blockIdx.x;          // 0..63
    const int qt   = 15 - blockIdx.y;     // reversed: heavy blocks first
    const int h    = bh & (NH_-1);
    const int b    = bh >> 4;
    const int q0   = qt * 64;

    const float lv   = lam[0];
    const float coef = (lv > 1e-8f ? lv : 0.f) * __expf(phv[h]);

    const char* kcB = (const char*)Kcb  + (size_t)bh*1024*128;
    const char* ksB = (const char*)Ksb  + (size_t)bh*1024*128;
    const char* vtB = (const char*)Vtb  + (size_t)bh*64*2048;
    const char* vsB = (const char*)Vstb + (size_t)bh*64*2048;

    // staging addressing (per-lane, constant across tiles)
    const int strow0 = wid*16 + (lane>>3);        // c=0 row; c=1 adds 8
    const size_t dsto0 = (size_t)wid*2048;        // c=0 dst;  c=1 adds 1024

    auto STAGE = [&](int kt, int buf) {
        const bool pvn = (kt <= qt);
        #pragma unroll
        for (int c = 0; c < 2; ++c) {
            int trow = strow0 + c*8;
            int sc_  = (lane&7) ^ (trow&7);
            size_t dsto = dsto0 + c*1024;
            gld16(kcB + ((size_t)(kt*64 + trow))*128 + sc_*16, (char*)sKC[buf] + dsto);
            gld16(ksB + ((size_t)(kt*64 + trow))*128 + sc_*16, (char*)sKS[buf] + dsto);
            if (pvn) {
                gld16(vtB + (size_t)trow*2048 + kt*128 + sc_*16, (char*)sVC[buf] + dsto);
                gld16(vsB + (size_t)trow*2048 + kt*128 + sc_*16, (char*)sVS[buf] + dsto);
            }
        }
    };

    // Q fragments direct from global bf16
    bf16x8 qcf[2], qsf[2];
    {
        int row = q0 + wid*16 + lr;
        size_t qb = ((size_t)bh*1024 + row)*64;
        #pragma unroll
        for (int hf = 0; hf < 2; ++hf) {
            qcf[hf] = *(const bf16x8*)&Qcb[qb + hf*32 + lg*8];
            qsf[hf] = *(const bf16x8*)&Qsb[qb + hf*32 + lg*8];
        }
    }

    f32x4 Oc[4], Os[4];
    #pragma unroll
    for (int n = 0; n < 4; ++n) { Oc[n] = (f32x4){0,0,0,0}; Os[n] = (f32x4){0,0,0,0}; }

    float m4[4], l4[4];
    float sc_s[4] = {}, qq_c[4] = {}, ss_s[4] = {}, qq_s[4] = {};
    #pragma unroll
    for (int i = 0; i < 4; ++i) { m4[i] = -INFINITY; l4[i] = 0.f; }

    // prologue: stage tile 0, drain, then pipeline
    STAGE(0, 0);
    __syncthreads();

    int cur = 0;
    for (int kt = 0; kt < 16; ++kt) {
        const bool pv = (kt <= qt);
        // ---- issue next tile's loads into the alternate buffer
        if (kt < 15) STAGE(kt + 1, cur ^ 1);

        // ---- S = Q K^T both streams + stats (reads buffer `cur`)
        float L[4][4];   // [n][r]
        #pragma unroll
        for (int n = 0; n < 4; ++n) {
            int krow = n*16 + lr;
            int rswz = krow & 7;
            const char* pc = (const char*)sKC[cur] + krow*128;
            const char* ps = (const char*)sKS[cur] + krow*128;
            bf16x8 kc0 = *(const bf16x8*)(pc + (((lg  ) ^ rswz)<<4));
            bf16x8 kc1 = *(const bf16x8*)(pc + (((lg+4) ^ rswz)<<4));
            bf16x8 ks0 = *(const bf16x8*)(ps + (((lg  ) ^ rswz)<<4));
            bf16x8 ks1 = *(const bf16x8*)(ps + (((lg+4) ^ rswz)<<4));
            f32x4 z = {0.f,0.f,0.f,0.f};
            f32x4 sc = mfma16(qcf[1], kc1, mfma16(qcf[0], kc0, z));
            f32x4 ss = mfma16(qsf[1], ks1, mfma16(qsf[0], ks0, z));
            #pragma unroll
            for (int r = 0; r < 4; ++r) {
                sc_s[r] += sc[r];
                qq_c[r] = fmaf(sc[r], sc[r], qq_c[r]);
                ss_s[r] += ss[r];
                qq_s[r] = fmaf(ss[r], ss[r], qq_s[r]);
                L[n][r] = 0.125f * fmaf(coef, ss[r], sc[r]);
            }
        }

        if (pv) {
            // ---- causal mask on diagonal tile
            if (kt == qt) {
                #pragma unroll
                for (int n = 0; n < 4; ++n) {
                    int kc = n*16 + lr;
                    #pragma unroll
                    for (int r = 0; r < 4; ++r)
                        if (kc > wid*16 + lg*4 + r) L[n][r] = -INFINITY;
                }
            }

            // ---- online softmax (rows = lg*4+r, cols split across 16 lr-lanes)
            float fr4[4];
            #pragma unroll
            for (int r = 0; r < 4; ++r) {
                float v = fmaxf(fmaxf(L[0][r], L[1][r]), fmaxf(L[2][r], L[3][r]));
                v = fmaxf(v, __shfl_xor(v, 1));
                v = fmaxf(v, __shfl_xor(v, 2));
                v = fmaxf(v, __shfl_xor(v, 4));
                v = fmaxf(v, __shfl_xor(v, 8));
                float mn = fmaxf(m4[r], v);
                float fr = __expf(m4[r] - mn);
                m4[r] = mn; fr4[r] = fr;
                float ps = 0.f;
                #pragma unroll
                for (int n = 0; n < 4; ++n) {
                    float p = __expf(L[n][r] - mn);
                    L[n][r] = p;
                    ps += p;
                }
                l4[r] = l4[r]*fr + ps;
            }
            #pragma unroll
            for (int n = 0; n < 4; ++n)
                #pragma unroll
                for (int r = 0; r < 4; ++r) {
                    Oc[n][r] *= fr4[r];
                    Os[n][r] *= fr4[r];
                }

            // ---- P -> wave-local LDS strip (bf16, swizzled)
            #pragma unroll
            for (int n = 0; n < 4; ++n)
                #pragma unroll
                for (int r = 0; r < 4; ++r) {
                    int prow = wid*16 + lg*4 + r;
                    *((__bf16*)((char*)sP + prow*128 + ((((n*16+lr)>>3) ^ (prow&7))<<4) + (((n*16+lr)&7)<<1))) = (__bf16)L[n][r];
                }

            // ---- O += P V (both streams)
            bf16x8 pa[2];
            {
                int prow = wid*16 + lr;
                const char* pp = (const char*)sP + prow*128;
                pa[0] = *(const bf16x8*)(pp + (((lg  ) ^ (prow&7))<<4));
                pa[1] = *(const bf16x8*)(pp + (((lg+4) ^ (prow&7))<<4));
            }
            #pragma unroll
            for (int n = 0; n < 4; ++n) {
                int vrow = n*16 + lr;
                int rswz = vrow & 7;
                const char* pc = (const char*)sVC[cur] + vrow*128;
                const char* ps = (const char*)sVS[cur] + vrow*128;
                bf16x8 vc0 = *(const bf16x8*)(pc + (((lg  ) ^ rswz)<<4));
                bf16x8 vc1 = *(const bf16x8*)(pc + (((lg+4) ^ rswz)<<4));
                bf16x8 vs0 = *(const bf16x8*)(ps + (((lg  ) ^ rswz)<<4));
                bf16x8 vs1 = *(const bf16x8*)(ps + (((lg+4) ^ rswz)<<4));
                Oc[n] = mfma16(pa[1], vc1, mfma16(pa[0], vc0, Oc[n]));
                Os[n] = mfma16(pa[1], vs1, mfma16(pa[0], vs0, Os[n]));
            }
        }

        // ---- one barrier per tile: drains next-tile loads (covered by compute)
        // and fences all waves' reads of buffer `cur`
        __syncthreads();
        cur ^= 1;
    }

    // ---- d2 partial (per-lane cols are disjoint)
    float d2p = qq_s[0] + qq_s[1] + qq_s[2] + qq_s[3];

    // ---- reduce row stats across 16 lr-lanes
    #pragma unroll
    for (int r = 0; r < 4; ++r) {
        #pragma unroll
        for (int msk = 1; msk <= 8; msk <<= 1) {
            l4[r]   += __shfl_xor(l4[r],   msk);
            sc_s[r] += __shfl_xor(sc_s[r], msk);
            qq_c[r] += __shfl_xor(qq_c[r], msk);
            ss_s[r] += __shfl_xor(ss_s[r], msk);
            qq_s[r] += __shfl_xor(qq_s[r], msk);
        }
    }

    // ---- outputs (ctx as hi/lo bf16 split; out2 f32)
    #pragma unroll
    for (int r = 0; r < 4; ++r) {
        float linv = 1.0f / l4[r];
        int row = q0 + wid*16 + lg*4 + r;
        #pragma unroll
        for (int n = 0; n < 4; ++n) {
            int d = n*16 + lr;
            float oc = Oc[n][r] * linv;
            size_t cidx = (((size_t)b*T_ + row)*NH_ + h)*64 + d;
            __bf16 hv = (__bf16)oc;
            ctxH[cidx] = hv;
            ctxL[cidx] = (__bf16)(oc - (float)hv);
            out2[((size_t)bh*T_ + row)*64 + d] = Os[n][r] * linv;
        }
    }

    // ---- row-std ratios (rows replicated on 16 lanes -> 1/16 weight)
    float rp = 0.f;
    #pragma unroll
    for (int r = 0; r < 4; ++r) {
        float S1c = 0.125f    * sc_s[r];
        float S2c = 0.015625f * qq_c[r];
        float S1s = 0.125f    * ss_s[r];
        float S2s = 0.015625f * qq_s[r];
        float varc = (S2c - S1c*S1c*(1.f/1024.f)) * (1.f/1023.f);
        float vars = (S2s - S1s*S1s*(1.f/1024.f)) * (1.f/1023.f);
        rp += sqrtf(fmaxf(vars, 0.f)) / (sqrtf(fmaxf(varc, 0.f)) + 1e-6f);
    }
    rp *= (1.f/16.f);

    #pragma unroll
    for (int msk = 1; msk <= 32; msk <<= 1) {
        d2p += __shfl_xor(d2p, msk);
        rp  += __shfl_xor(rp,  msk);
    }
    __syncthreads();                      // all waves done with LDS
    float* sred = (float*)sP;
    if (lane == 0) { sred[wid] = d2p; sred[4+wid] = rp; }
    __syncthreads();
    if (tid == 0) {
        float td2 = (sred[0]+sred[1]+sred[2]+sred[3]) * coef * coef * 0.015625f;
        float tr  =  sred[4]+sred[5]+sred[6]+sred[7];
        atomicAdd(&accum[0], td2);
        atomicAdd(&accum[1], tr);
    }
}

// ---------------------------------------------------------------- finalize scalars
__global__ void k_fin(const float* __restrict__ acc, float* __restrict__ out) {
    if (threadIdx.x == 0) {
        out[0] = sqrtf(acc[0] * (1.f/67108864.f));   // / (B*NH*T*T)
        out[1] = acc[1] * (1.f/65536.f);             // / (B*NH*T)
    }
}

extern "C" void kernel_launch(void* const* d_in, const int* in_sizes, int n_in,
                              void* d_out, int out_size, void* d_ws, size_t ws_size,
                              hipStream_t stream)
{
    const float* data  = (const float*)d_in[0];
    const float* sin_  = (const float*)d_in[1];
    const float* qkv_w = (const float*)d_in[2];
    const float* qkv_b = (const float*)d_in[3];
    const float* out_w = (const float*)d_in[4];
    const float* out_b = (const float*)d_in[5];
    const float* Wq    = (const float*)d_in[6];
    const float* Wk    = (const float*)d_in[7];
    const float* Wv    = (const float*)d_in[8];
    const float* lam   = (const float*)d_in[9];
    const float* phv   = (const float*)d_in[10];
    float* out = (float*)d_out;
    char*  w   = (char*)d_ws;

    const size_t MB = 1024*1024;
    __bf16* Qcb   = (__bf16*)(w);             // 8 MB each
    __bf16* Kcb   = (__bf16*)(w + 8*MB);
    __bf16* Vtb   = (__bf16*)(w + 16*MB);
    __bf16* Qsb   = (__bf16*)(w + 24*MB);
    __bf16* Ksb   = (__bf16*)(w + 32*MB);
    __bf16* Vstb  = (__bf16*)(w + 40*MB);
    __bf16* dataH = (__bf16*)(w + 48*MB);     // aliased as ctxH after qkv GEMM
    __bf16* dataL = (__bf16*)(w + 56*MB);     // aliased as ctxL
    __bf16* wH    = (__bf16*)(w + 64*MB);     // 6 MB each
    __bf16* wL    = (__bf16*)(w + 70*MB);
    __bf16* owH   = (__bf16*)(w + 76*MB);     // 2 MB each
    __bf16* owL   = (__bf16*)(w + 78*MB);
    float*  accum = (float*)(w + 80*MB);

    k_zero   <<<1, 64, 0, stream>>>(accum);
    k_split  <<<2048, 256, 0, stream>>>(data, dataH, dataL, qkv_w, wH, wL, out_w, owH, owL);
    k_gemm<0><<<dim3(24, 32), 256, 0, stream>>>(dataH, dataL, wH, wL, qkv_b, Qcb, Kcb, Vtb, nullptr);
    k_sproj  <<<dim3(8, 64), 256, 0, stream>>>(sin_, Wq, Wk, Wv, Qsb, Ksb, Vstb);
    k_attn   <<<dim3(64, 16), 256, 0, stream>>>(Qcb, Kcb, Vtb, Qsb, Ksb, Vstb, lam, phv,
                                                dataH, dataL, out + (size_t)MSZ, accum);
    k_gemm<1><<<dim3(8, 32), 256, 0, stream>>>(dataH, dataL, owH, owL, out_b, nullptr, nullptr, nullptr, out);
    k_fin    <<<1, 64, 0, stream>>>(accum, out + 2*(size_t)MSZ);
}